// Round 1
// 1793.202 us; speedup vs baseline: 1.7691x; 1.7691x over previous
//
#include <hip/hip_runtime.h>
#include <hip/hip_bf16.h>

typedef __hip_bfloat16 bf16;
typedef _Float16 f16;
typedef __attribute__((ext_vector_type(8))) _Float16 f16x8;
typedef __attribute__((ext_vector_type(2))) _Float16 f16x2;
typedef __attribute__((ext_vector_type(4))) float f32x4;

// ---------- small device helpers ----------
__device__ __forceinline__ unsigned short f2bfu(float f) {
    __hip_bfloat16 h = __float2bfloat16(f);
    return *reinterpret_cast<unsigned short*>(&h);
}
__device__ __forceinline__ float us2f(unsigned short u) {
    unsigned int x = ((unsigned int)u) << 16;
    float f;
    __builtin_memcpy(&f, &x, 4);
    return f;
}
__device__ __forceinline__ float geluf(float x) {
    return 0.5f * x * (1.0f + erff(x * 0.70710678118654752440f));
}
__device__ __forceinline__ float sigmf(float x) { return 1.0f / (1.0f + __expf(-x)); }

// Sizes (fixed by the problem)
#define NB 16
#define NC 128
#define NH 128
#define NW 128
#define PLANE (NH * NW)          // 16384
#define NSTAT 262144.0f          // B*H*W per-channel BN count

// f16 weights in device-global memory (no workspace-size assumptions).
// g_Wc layout: [tap(9)][chunk(4)][co(128)][ci_in_chunk(32)]
// g_Wsc layout: [chunk(4)][co(128)][ci_in_chunk(32)]
__device__ __align__(16) f16 g_Wc[9 * 4 * 128 * 32];
__device__ __align__(16) f16 g_Wsc[4 * 128 * 32];

// ---------- K0: convert conv1/sc weights to f16 in MFMA-friendly layout ----------
__global__ __launch_bounds__(256) void k_wprep(const float* __restrict__ c1w,
                                               const float* __restrict__ scw) {
    int i = blockIdx.x * 256 + threadIdx.x;
    if (i < 9 * 4 * 128 * 32) {
        int tap = i / 16384;
        int rem = i - tap * 16384;
        int chunk = rem >> 12;
        int r2 = rem & 4095;
        int co = r2 >> 5;
        int cil = r2 & 31;
        int ci = chunk * 32 + cil;
        g_Wc[i] = (f16)c1w[((size_t)co * 128 + ci) * 9 + tap];
    } else if (i < 9 * 4 * 128 * 32 + 4 * 128 * 32) {
        int j = i - 9 * 4 * 128 * 32;
        int chunk = j >> 12;
        int r2 = j & 4095;
        int co = r2 >> 5;
        int cil = r2 & 31;
        g_Wsc[j] = (f16)scw[(size_t)co * 128 + chunk * 32 + cil];
    }
}

// ---------- K1: h = gelu(dce_flat @ W1 + b1), [16,128] ----------
__global__ __launch_bounds__(256) void k_dce1(const float* __restrict__ dce,
                                              const float* __restrict__ W1,
                                              const float* __restrict__ b1,
                                              float* __restrict__ out_h) {
    int b = blockIdx.x;
    int t = threadIdx.x;
    int j = t & 127;
    int half = t >> 7;
    __shared__ float sdce[12800];
    __shared__ float sred[256];
    const float* drow = dce + (size_t)b * 12800;
    for (int i = t; i < 3200; i += 256) {
        float4 v = *(const float4*)&drow[i * 4];
        *(float4*)&sdce[i * 4] = v;
    }
    __syncthreads();
    float acc = 0.0f;
    int k0 = half * 6400;
    const float* Wp = W1 + (size_t)k0 * 128 + j;
    for (int k = 0; k < 6400; ++k) acc += sdce[k0 + k] * Wp[(size_t)k * 128];
    sred[t] = acc;
    __syncthreads();
    if (t < 128) {
        float v = sred[t] + sred[t + 128] + b1[j];
        out_h[b * 128 + j] = geluf(v);
    }
}

// ---------- K2: dce_feat = h @ W2 + b2, [16,128] ----------
__global__ __launch_bounds__(128) void k_dce2(const float* __restrict__ h,
                                              const float* __restrict__ W2,
                                              const float* __restrict__ b2,
                                              float* __restrict__ feat) {
    int b = blockIdx.x, j = threadIdx.x;
    __shared__ float sh[128];
    sh[j] = h[b * 128 + j];
    __syncthreads();
    float acc = b2[j];
    for (int k = 0; k < 128; ++k) acc += sh[k] * W2[k * 128 + j];
    feat[b * 128 + j] = acc;
}

// ---------- K3: spatial features via border-corrected sums ----------
__global__ __launch_bounds__(256) void k_spatial(const float* __restrict__ x,
                                                 const float* __restrict__ dw,
                                                 float* __restrict__ spat) {
    int bc = blockIdx.x;  // b*128+c
    int t = threadIdx.x;
    const float* p = x + (size_t)bc * PLANE;
    float f = 0, r0 = 0, r1 = 0, c0 = 0, c1 = 0;
    for (int i = t; i < PLANE; i += 256) {
        float v = p[i];
        int row = i >> 7, col = i & 127;
        f += v;
        if (row == 0) r0 += v;
        if (row == 127) r1 += v;
        if (col == 0) c0 += v;
        if (col == 127) c1 += v;
    }
    __shared__ float s[256];
    __shared__ float red[5];
    float vals[5] = {f, r0, r1, c0, c1};
    for (int k = 0; k < 5; ++k) {
        s[t] = vals[k];
        __syncthreads();
        for (int o = 128; o > 0; o >>= 1) {
            if (t < o) s[t] += s[t + o];
            __syncthreads();
        }
        if (t == 0) red[k] = s[0];
        __syncthreads();
    }
    if (t == 0) {
        int c = bc & 127;
        float full = red[0], row0 = red[1], row127 = red[2], col0 = red[3], col127 = red[4];
        float x00 = p[0];
        float x0e = p[127];
        float xe0 = p[127 * 128];
        float xee = p[127 * 128 + 127];
        float acc = 0.0f;
        for (int kh = 0; kh < 3; ++kh)
            for (int kw = 0; kw < 3; ++kw) {
                int dh = kh - 1, dwv = kw - 1;
                float T = full;
                if (dh == -1) T -= row127;
                else if (dh == 1) T -= row0;
                if (dwv == -1) T -= col127;
                else if (dwv == 1) T -= col0;
                if (dh == -1 && dwv == -1) T += xee;
                if (dh == -1 && dwv == 1) T += xe0;
                if (dh == 1 && dwv == -1) T += x0e;
                if (dh == 1 && dwv == 1) T += x00;
                acc += dw[c * 9 + kh * 3 + kw] * T;
            }
        spat[bc] = acc * (1.0f / 16384.0f);
    }
}

// ---------- K4: SE modulation -> mod_w [16,128] ----------
__global__ __launch_bounds__(128) void k_mod(const float* __restrict__ feat,
                                             const float* __restrict__ spat,
                                             const float* __restrict__ Wsh,
                                             const float* __restrict__ bsh,
                                             const float* __restrict__ Wex,
                                             const float* __restrict__ bex,
                                             float* __restrict__ mod) {
    int b = blockIdx.x, t = threadIdx.x;
    __shared__ float sm[128], ssh[64];
    sm[t] = feat[b * 128 + t] * spat[b * 128 + t];
    __syncthreads();
    if (t < 64) {
        float acc = bsh[t];
        for (int c = 0; c < 128; ++c) acc += sm[c] * Wsh[c * 64 + t];
        ssh[t] = geluf(acc);
    }
    __syncthreads();
    float acc = bex[t];
    for (int k = 0; k < 64; ++k) acc += ssh[k] * Wex[k * 128 + t];
    mod[b * 128 + t] = sigmf(acc);
}

// ---------- K5 (MFMA): conv1 3x3 + sc 1x1 stats via f16 matrix cores ----------
// One block per (b,h). 4 waves in a 2x2 grid, each wave computes a 64co x 64w
// tile of the output row via 4x4 fragments of mfma_f32_16x16x32_f16.
// K-sequence: 4 ci-chunks of 32, 9 taps each, + Wsc "tap" (reuses center-tap
// B fragments) accumulated into a separate asc for the shortcut BN stats.
__global__ __launch_bounds__(256, 2) void k_conv1m(const float* __restrict__ x,
                                                   const float* __restrict__ mod,
                                                   float* __restrict__ y1,
                                                   float* __restrict__ stats) {
    int bid = blockIdx.x;          // b*128 + h
    int h = bid & 127;
    int b = bid >> 7;
    int t = threadIdx.x;
    int lane = t & 63;
    int wv = t >> 6;
    int l15 = lane & 15, lg = lane >> 4;
    int co_half = (wv >> 1) * 64;
    int w_half = (wv & 1) * 64;

    // x tile: [row(3)][w slot(130: w=-1..128)][ci(32)+pad(8)] f16, stride 80B
    __shared__ f16 xs[3][130][40];   // 31200 B
    __shared__ f16 wl[4096];         // [co(128)][ci(32)] current tap, 8 KB
    __shared__ f16 wsl[4096];        // Wsc chunk, 8 KB

    f32x4 acc[4][4], asc[4][4];
#pragma unroll
    for (int ct = 0; ct < 4; ++ct)
#pragma unroll
        for (int wt = 0; wt < 4; ++wt) {
            acc[ct][wt] = (f32x4){0.f, 0.f, 0.f, 0.f};
            asc[ct][wt] = (f32x4){0.f, 0.f, 0.f, 0.f};
        }

    const float* xb = x + (size_t)b * 128 * PLANE;
    const float* modb = mod + b * 128;

    for (int chunk = 0; chunk < 4; ++chunk) {
        __syncthreads();  // previous chunk's xs/wsl reads done

        // ---- stage x chunk: transpose [ci][w] -> [w][ci], *mod, ->f16 ----
        // item id -> p (ci-pair 0..15), g (w4 group 0..31), r (row 0..2)
#pragma unroll
        for (int it = 0; it < 6; ++it) {
            int id = t + it * 256;
            int p = id & 15;
            int g = (id >> 4) & 31;
            int r = id >> 9;
            int hp = h + r - 1;
            int ci = chunk * 32 + p * 2;
            f16x2* dst = (f16x2*)&xs[r][g * 4 + 1][p * 2];  // w-slot stride = 20 f16x2
            if ((unsigned)hp < 128u) {
                const float* s0 = xb + (size_t)ci * PLANE + hp * 128 + g * 4;
                float4 va = *(const float4*)s0;
                float4 vb = *(const float4*)(s0 + PLANE);
                float m0 = modb[ci], m1 = modb[ci + 1];
                dst[0]  = (f16x2){(f16)(va.x * m0), (f16)(vb.x * m1)};
                dst[20] = (f16x2){(f16)(va.y * m0), (f16)(vb.y * m1)};
                dst[40] = (f16x2){(f16)(va.z * m0), (f16)(vb.z * m1)};
                dst[60] = (f16x2){(f16)(va.w * m0), (f16)(vb.w * m1)};
            } else {
                f16x2 z = (f16x2){(f16)0.f, (f16)0.f};
                dst[0] = z; dst[20] = z; dst[40] = z; dst[60] = z;
            }
        }
        // zero halo slots w=-1 (slot 0) and w=128 (slot 129)
        if (t < 120) {
            int r = t / 40, rem = t % 40;
            int slot = (rem < 20) ? 0 : 129;
            int k2 = (rem % 20) * 2;
            *(f16x2*)&xs[r][slot][k2] = (f16x2){(f16)0.f, (f16)0.f};
        }
        // ---- stage Wsc chunk (8 KB linear copy) ----
        {
            const uint4* src = (const uint4*)&g_Wsc[chunk * 4096];
            uint4* dst = (uint4*)wsl;
            dst[t] = src[t];
            dst[t + 256] = src[t + 256];
        }

        for (int tap = 0; tap < 9; ++tap) {
            if (tap) __syncthreads();  // prior tap's wl reads done
            {
                const uint4* src = (const uint4*)&g_Wc[(size_t)(tap * 4 + chunk) * 4096];
                uint4* dst = (uint4*)wl;
                dst[t] = src[t];
                dst[t + 256] = src[t + 256];
            }
            __syncthreads();           // staging visible (x+wsl too on tap 0)

            int kh = (tap >= 6) ? 2 : ((tap >= 3) ? 1 : 0);
            int kw = tap - kh * 3;

            f16x8 af[4], bf[4];
#pragma unroll
            for (int ct = 0; ct < 4; ++ct)
                af[ct] = *(const f16x8*)&wl[(co_half + ct * 16 + l15) * 32 + lg * 8];
#pragma unroll
            for (int wt = 0; wt < 4; ++wt)
                bf[wt] = *(const f16x8*)&xs[kh][w_half + wt * 16 + l15 + kw][lg * 8];
#pragma unroll
            for (int ct = 0; ct < 4; ++ct)
#pragma unroll
                for (int wt = 0; wt < 4; ++wt)
                    acc[ct][wt] = __builtin_amdgcn_mfma_f32_16x16x32_f16(
                        af[ct], bf[wt], acc[ct][wt], 0, 0, 0);

            if (tap == 4) {  // center tap: same B frags feed the 1x1 shortcut
                f16x8 sf[4];
#pragma unroll
                for (int ct = 0; ct < 4; ++ct)
                    sf[ct] = *(const f16x8*)&wsl[(co_half + ct * 16 + l15) * 32 + lg * 8];
#pragma unroll
                for (int ct = 0; ct < 4; ++ct)
#pragma unroll
                    for (int wt = 0; wt < 4; ++wt)
                        asc[ct][wt] = __builtin_amdgcn_mfma_f32_16x16x32_f16(
                            sf[ct], bf[wt], asc[ct][wt], 0, 0, 0);
            }
        }
    }

    // ---- epilogue: write y1 (fp32) + bn1/bnsc stats ----
    float* yb = y1 + (size_t)b * 128 * PLANE + (size_t)h * 128;
#pragma unroll
    for (int ct = 0; ct < 4; ++ct) {
#pragma unroll
        for (int r = 0; r < 4; ++r) {
            int co = co_half + ct * 16 + lg * 4 + r;
            float s = 0, q = 0, ss = 0, qq = 0;
#pragma unroll
            for (int wt = 0; wt < 4; ++wt) {
                float v = acc[ct][wt][r];
                yb[(size_t)co * PLANE + w_half + wt * 16 + l15] = v;
                s += v; q += v * v;
                float u = asc[ct][wt][r];
                ss += u; qq += u * u;
            }
#pragma unroll
            for (int o = 1; o < 16; o <<= 1) {
                s += __shfl_xor(s, o);
                q += __shfl_xor(q, o);
                ss += __shfl_xor(ss, o);
                qq += __shfl_xor(qq, o);
            }
            if (l15 == 0) {
                atomicAdd(&stats[co], s);
                atomicAdd(&stats[128 + co], q);
                atomicAdd(&stats[256 + co], ss);
                atomicAdd(&stats[384 + co], qq);
            }
        }
    }
}

// ---------- K6: finalize bn1 + bnsc -> affine coefs ----------
__global__ __launch_bounds__(256) void k_fin1(const float* __restrict__ stats,
                                              const float* __restrict__ g1, const float* __restrict__ be1,
                                              const float* __restrict__ gsc, const float* __restrict__ bsc,
                                              float* __restrict__ coef) {
    int t = threadIdx.x;
    const float inv = 1.0f / NSTAT;
    if (t < 128) {
        float m = stats[t] * inv;
        float v = stats[128 + t] * inv - m * m;
        float a = g1[t] * rsqrtf(v + 1e-5f);
        coef[t] = a;
        coef[128 + t] = be1[t] - m * a;
    } else {
        int c = t - 128;
        float m = stats[256 + c] * inv;
        float v = stats[384 + c] * inv - m * m;
        float a = gsc[c] * rsqrtf(v + 1e-5f);
        coef[256 + c] = a;
        coef[384 + c] = bsc[c] - m * a;
    }
}

// ---------- K7: conv2 (1x1) over bb=silu(bn1(y1)) -> bn2 stats only ----------
__global__ __launch_bounds__(256) void k_conv2stats(const float* __restrict__ y1,
                                                    const float* __restrict__ w2,
                                                    const float* __restrict__ coef,
                                                    float* __restrict__ stats) {
    int bid = blockIdx.x;
    int cog = bid & 3;
    int h = (bid >> 2) & 127;
    int b = bid >> 9;
    int t = threadIdx.x;
    int w_i = t & 31, co_i = t >> 5;
    int wb = w_i * 4;
    __shared__ float A2[16][128];
    __shared__ float W2L[512];
    float acc[4][4];
#pragma unroll
    for (int a = 0; a < 4; ++a)
#pragma unroll
        for (int i = 0; i < 4; ++i) acc[a][i] = 0.0f;

    for (int cc = 0; cc < 8; ++cc) {
        __syncthreads();
        for (int e = t; e < 2048; e += 256) {
            int ci = e >> 7, col = e & 127;
            int cig = cc * 16 + ci;
            float v = y1[(((size_t)b * 128 + cig) * 128 + h) * 128 + col];
            v = coef[cig] * v + coef[128 + cig];
            A2[ci][col] = v * sigmf(v);
        }
        for (int e = t; e < 512; e += 256) {
            int co_l = e & 31, ci = e >> 5;
            W2L[e] = w2[(size_t)(cog * 32 + co_l) * 128 + cc * 16 + ci];
        }
        __syncthreads();
        for (int ci = 0; ci < 16; ++ci) {
            float4 win = *(const float4*)&A2[ci][wb];
            float4 wv = *(const float4*)&W2L[ci * 32 + co_i * 4];
            float w0 = win.x, w1v = win.y, w2v = win.z, w3 = win.w;
            acc[0][0] += wv.x * w0; acc[0][1] += wv.x * w1v; acc[0][2] += wv.x * w2v; acc[0][3] += wv.x * w3;
            acc[1][0] += wv.y * w0; acc[1][1] += wv.y * w1v; acc[1][2] += wv.y * w2v; acc[1][3] += wv.y * w3;
            acc[2][0] += wv.z * w0; acc[2][1] += wv.z * w1v; acc[2][2] += wv.z * w2v; acc[2][3] += wv.z * w3;
            acc[3][0] += wv.w * w0; acc[3][1] += wv.w * w1v; acc[3][2] += wv.w * w2v; acc[3][3] += wv.w * w3;
        }
    }
#pragma unroll
    for (int c4 = 0; c4 < 4; ++c4) {
        int co = cog * 32 + co_i * 4 + c4;
        float s = 0, q = 0;
#pragma unroll
        for (int i = 0; i < 4; ++i) {
            float v = acc[c4][i];
            s += v; q += v * v;
        }
#pragma unroll
        for (int o = 1; o < 32; o <<= 1) {
            s += __shfl_xor(s, o);
            q += __shfl_xor(q, o);
        }
        if ((t & 31) == 0) {
            atomicAdd(&stats[512 + co], s);
            atomicAdd(&stats[640 + co], q);
        }
    }
}

// ---------- K8: finalize bn2 ----------
__global__ __launch_bounds__(128) void k_fin2(const float* __restrict__ stats,
                                              const float* __restrict__ g2, const float* __restrict__ be2,
                                              float* __restrict__ coef) {
    int c = threadIdx.x;
    const float inv = 1.0f / NSTAT;
    float m = stats[512 + c] * inv;
    float v = stats[640 + c] * inv - m * m;
    float a = g2[c] * rsqrtf(v + 1e-5f);
    coef[512 + c] = a;
    coef[640 + c] = be2[c] - m * a;
}

// ---------- K9: slice-local final: out = silu(bn2(conv2(bb)) + bnsc(sc(xm))) ----------
__global__ __launch_bounds__(256) void k_final(const float* __restrict__ x,
                                               float* yio,
                                               const float* __restrict__ w2,
                                               const float* __restrict__ wsc,
                                               const float* __restrict__ mod,
                                               const float* __restrict__ coef) {
    int bid = blockIdx.x;  // b*128 + h
    int h = bid & 127;
    int b = bid >> 7;
    int t = threadIdx.x;
    int w_i = t & 31, co_i = t >> 5;   // co_i in 0..7 -> 16 co each
    int wb = w_i * 4;
    int cb = co_i * 16;

    __shared__ unsigned short bb_s[128][128];  // 32 KB post-bn1-silu (bf16)
    __shared__ float AX[16][128];              // 8 KB xm chunk
    __shared__ float W2L[16 * 128];            // 8 KB [co][ci16]
    __shared__ float WSL[16 * 128];            // 8 KB

    // stage full bb slice BEFORE any global writes
    for (int e = t; e < 16384; e += 256) {
        int ci = e >> 7, col = e & 127;
        float v = yio[(((size_t)b * 128 + ci) * 128 + h) * 128 + col];
        v = coef[ci] * v + coef[128 + ci];
        v = v * sigmf(v);
        bb_s[ci][col] = f2bfu(v);
    }

    float acc2[16][4], accs[16][4];
#pragma unroll
    for (int j = 0; j < 16; ++j)
#pragma unroll
        for (int i = 0; i < 4; ++i) { acc2[j][i] = 0.0f; accs[j][i] = 0.0f; }

    for (int cc = 0; cc < 8; ++cc) {
        __syncthreads();
        for (int e = t; e < 2048; e += 256) {
            int ci = e >> 7, col = e & 127;
            int cig = cc * 16 + ci;
            AX[ci][col] = x[(((size_t)b * 128 + cig) * 128 + h) * 128 + col] * mod[b * 128 + cig];
        }
        for (int e = t; e < 2048; e += 256) {
            int co = e >> 4, ci = e & 15;
            W2L[e] = w2[(size_t)co * 128 + cc * 16 + ci];
            WSL[e] = wsc[(size_t)co * 128 + cc * 16 + ci];
        }
        __syncthreads();

        for (int ci = 0; ci < 16; ++ci) {
            ushort4 bu = *(const ushort4*)&bb_s[cc * 16 + ci][wb];
            float a0 = us2f(bu.x), a1 = us2f(bu.y), a2 = us2f(bu.z), a3 = us2f(bu.w);
            float4 xv = *(const float4*)&AX[ci][wb];
#pragma unroll
            for (int j = 0; j < 16; ++j) {
                float wv = W2L[(cb + j) * 16 + ci];
                float sv = WSL[(cb + j) * 16 + ci];
                acc2[j][0] += wv * a0; acc2[j][1] += wv * a1; acc2[j][2] += wv * a2; acc2[j][3] += wv * a3;
                accs[j][0] += sv * xv.x; accs[j][1] += sv * xv.y; accs[j][2] += sv * xv.z; accs[j][3] += sv * xv.w;
            }
        }
    }

#pragma unroll
    for (int j = 0; j < 16; ++j) {
        int co = cb + j;
        float a2c = coef[512 + co], c2c = coef[640 + co];
        float asc = coef[256 + co], csc = coef[384 + co];
        float4 pk;
        float r[4];
#pragma unroll
        for (int i = 0; i < 4; ++i) {
            float v = a2c * acc2[j][i] + c2c + asc * accs[j][i] + csc;
            r[i] = v * sigmf(v);
        }
        pk.x = r[0]; pk.y = r[1]; pk.z = r[2]; pk.w = r[3];
        *(float4*)(yio + (((size_t)b * 128 + co) * 128 + h) * 128 + wb) = pk;
    }
}

// ---------- launcher ----------
extern "C" void kernel_launch(void* const* d_in, const int* in_sizes, int n_in,
                              void* d_out, int out_size, void* d_ws, size_t ws_size,
                              hipStream_t stream) {
    (void)in_sizes; (void)n_in; (void)out_size; (void)ws_size;
    const float* x    = (const float*)d_in[0];
    const float* dce  = (const float*)d_in[1];
    const float* dwc  = (const float*)d_in[2];
    const float* W1   = (const float*)d_in[3];
    const float* b1   = (const float*)d_in[4];
    const float* W2d  = (const float*)d_in[5];
    const float* b2d  = (const float*)d_in[6];
    const float* Wsh  = (const float*)d_in[7];
    const float* bsh  = (const float*)d_in[8];
    const float* Wex  = (const float*)d_in[9];
    const float* bex  = (const float*)d_in[10];
    const float* c1w  = (const float*)d_in[11];
    const float* g1   = (const float*)d_in[12];
    const float* be1  = (const float*)d_in[13];
    const float* c2w  = (const float*)d_in[14];
    const float* g2   = (const float*)d_in[15];
    const float* be2  = (const float*)d_in[16];
    const float* scw  = (const float*)d_in[17];
    const float* gsc  = (const float*)d_in[18];
    const float* bsc  = (const float*)d_in[19];

    // small float scratch at start of d_ws (~39 KB) — y1 lives in d_out (fp32)
    float* F = (float*)d_ws;
    float* dh    = F;            // 2048
    float* feat  = F + 2048;     // 2048
    float* spat  = F + 4096;     // 2048
    float* md    = F + 6144;     // 2048
    float* stats = F + 8192;     // 768
    float* coef  = F + 8960;     // 768

    float* y1 = (float*)d_out;   // conv1 output staged in d_out, overwritten by k_final

    hipMemsetAsync(stats, 0, 768 * sizeof(float), stream);

    k_wprep<<<640, 256, 0, stream>>>(c1w, scw);
    k_dce1<<<16, 256, 0, stream>>>(dce, W1, b1, dh);
    k_dce2<<<16, 128, 0, stream>>>(dh, W2d, b2d, feat);
    k_spatial<<<2048, 256, 0, stream>>>(x, dwc, spat);
    k_mod<<<16, 128, 0, stream>>>(feat, spat, Wsh, bsh, Wex, bex, md);
    k_conv1m<<<2048, 256, 0, stream>>>(x, md, y1, stats);
    k_fin1<<<1, 256, 0, stream>>>(stats, g1, be1, gsc, bsc, coef);
    k_conv2stats<<<8192, 256, 0, stream>>>(y1, c2w, coef, stats);
    k_fin2<<<1, 128, 0, stream>>>(stats, g2, be2, coef);
    k_final<<<2048, 256, 0, stream>>>(x, y1, c2w, scw, md, coef);
}

// Round 2
// 1527.643 us; speedup vs baseline: 2.0766x; 1.1738x over previous
//
#include <hip/hip_runtime.h>
#include <hip/hip_bf16.h>

typedef _Float16 f16;
typedef __attribute__((ext_vector_type(8))) _Float16 f16x8;
typedef __attribute__((ext_vector_type(4))) float f32x4;

// ---------- small device helpers ----------
__device__ __forceinline__ float geluf(float x) {
    return 0.5f * x * (1.0f + erff(x * 0.70710678118654752440f));
}
__device__ __forceinline__ float sigmf(float x) { return 1.0f / (1.0f + __expf(-x)); }

// Sizes (fixed by the problem)
#define NB 16
#define NC 128
#define NH 128
#define NW 128
#define PLANE (NH * NW)          // 16384
#define NSTAT 262144.0f          // B*H*W per-channel BN count

// f16 weights / staged tensors in device-global memory (no workspace assumptions).
// g_Wc  layout: [tap(9)][chunk(4)][co(128)][ci_in_chunk(32)]
// g_Wsc layout: [chunk(4)][co(128)][ci_in_chunk(32)]
// g_W2  layout: [chunk(4)][co(128)][ci_in_chunk(32)]
// g_xmT layout: [b(16)][h(128)][chunk(4)][wslot(130)][ci(32)]  (slot s = input w+1; slots 0,129 zero)
__device__ __align__(16) f16 g_Wc[9 * 4 * 128 * 32];
__device__ __align__(16) f16 g_Wsc[4 * 128 * 32];
__device__ __align__(16) f16 g_W2[4 * 128 * 32];
__device__ __align__(16) f16 g_xmT[(size_t)16 * 128 * 4 * 130 * 32];

// ---------- K0: convert conv1/sc/conv2 weights to f16 in MFMA-friendly layout ----------
__global__ __launch_bounds__(256) void k_wprep(const float* __restrict__ c1w,
                                               const float* __restrict__ scw,
                                               const float* __restrict__ c2w) {
    int i = blockIdx.x * 256 + threadIdx.x;
    if (i < 147456) {                       // 9*4*128*32
        int tap = i / 16384;
        int rem = i - tap * 16384;
        int chunk = rem >> 12;
        int r2 = rem & 4095;
        int co = r2 >> 5;
        int cil = r2 & 31;
        int ci = chunk * 32 + cil;
        g_Wc[i] = (f16)c1w[((size_t)co * 128 + ci) * 9 + tap];
    } else if (i < 163840) {                // + 4*128*32
        int j = i - 147456;
        int chunk = j >> 12;
        int r2 = j & 4095;
        int co = r2 >> 5;
        int cil = r2 & 31;
        g_Wsc[j] = (f16)scw[(size_t)co * 128 + chunk * 32 + cil];
    } else if (i < 180224) {                // + 4*128*32
        int j = i - 163840;
        int chunk = j >> 12;
        int r2 = j & 4095;
        int co = r2 >> 5;
        int cil = j & 31;
        g_W2[j] = (f16)c2w[(size_t)co * 128 + chunk * 32 + cil];
    }
}

// ---------- K1: h = gelu(dce_flat @ W1 + b1), [16,128] ----------
__global__ __launch_bounds__(256) void k_dce1(const float* __restrict__ dce,
                                              const float* __restrict__ W1,
                                              const float* __restrict__ b1,
                                              float* __restrict__ out_h) {
    int b = blockIdx.x;
    int t = threadIdx.x;
    int j = t & 127;
    int half = t >> 7;
    __shared__ float sdce[12800];
    __shared__ float sred[256];
    const float* drow = dce + (size_t)b * 12800;
    for (int i = t; i < 3200; i += 256) {
        float4 v = *(const float4*)&drow[i * 4];
        *(float4*)&sdce[i * 4] = v;
    }
    __syncthreads();
    float acc = 0.0f;
    int k0 = half * 6400;
    const float* Wp = W1 + (size_t)k0 * 128 + j;
    for (int k = 0; k < 6400; ++k) acc += sdce[k0 + k] * Wp[(size_t)k * 128];
    sred[t] = acc;
    __syncthreads();
    if (t < 128) {
        float v = sred[t] + sred[t + 128] + b1[j];
        out_h[b * 128 + j] = geluf(v);
    }
}

// ---------- K2: dce_feat = h @ W2 + b2, [16,128] ----------
__global__ __launch_bounds__(128) void k_dce2(const float* __restrict__ h,
                                              const float* __restrict__ W2,
                                              const float* __restrict__ b2,
                                              float* __restrict__ feat) {
    int b = blockIdx.x, j = threadIdx.x;
    __shared__ float sh[128];
    sh[j] = h[b * 128 + j];
    __syncthreads();
    float acc = b2[j];
    for (int k = 0; k < 128; ++k) acc += sh[k] * W2[k * 128 + j];
    feat[b * 128 + j] = acc;
}

// ---------- K3: spatial features via border-corrected sums ----------
__global__ __launch_bounds__(256) void k_spatial(const float* __restrict__ x,
                                                 const float* __restrict__ dw,
                                                 float* __restrict__ spat) {
    int bc = blockIdx.x;  // b*128+c
    int t = threadIdx.x;
    const float* p = x + (size_t)bc * PLANE;
    float f = 0, r0 = 0, r1 = 0, c0 = 0, c1 = 0;
    for (int i = t; i < PLANE; i += 256) {
        float v = p[i];
        int row = i >> 7, col = i & 127;
        f += v;
        if (row == 0) r0 += v;
        if (row == 127) r1 += v;
        if (col == 0) c0 += v;
        if (col == 127) c1 += v;
    }
    __shared__ float s[256];
    __shared__ float red[5];
    float vals[5] = {f, r0, r1, c0, c1};
    for (int k = 0; k < 5; ++k) {
        s[t] = vals[k];
        __syncthreads();
        for (int o = 128; o > 0; o >>= 1) {
            if (t < o) s[t] += s[t + o];
            __syncthreads();
        }
        if (t == 0) red[k] = s[0];
        __syncthreads();
    }
    if (t == 0) {
        int c = bc & 127;
        float full = red[0], row0 = red[1], row127 = red[2], col0 = red[3], col127 = red[4];
        float x00 = p[0];
        float x0e = p[127];
        float xe0 = p[127 * 128];
        float xee = p[127 * 128 + 127];
        float acc = 0.0f;
        for (int kh = 0; kh < 3; ++kh)
            for (int kw = 0; kw < 3; ++kw) {
                int dh = kh - 1, dwv = kw - 1;
                float T = full;
                if (dh == -1) T -= row127;
                else if (dh == 1) T -= row0;
                if (dwv == -1) T -= col127;
                else if (dwv == 1) T -= col0;
                if (dh == -1 && dwv == -1) T += xee;
                if (dh == -1 && dwv == 1) T += xe0;
                if (dh == 1 && dwv == -1) T += x0e;
                if (dh == 1 && dwv == 1) T += x00;
                acc += dw[c * 9 + kh * 3 + kw] * T;
            }
        spat[bc] = acc * (1.0f / 16384.0f);
    }
}

// ---------- K4: SE modulation -> mod_w [16,128] ----------
__global__ __launch_bounds__(128) void k_mod(const float* __restrict__ feat,
                                             const float* __restrict__ spat,
                                             const float* __restrict__ Wsh,
                                             const float* __restrict__ bsh,
                                             const float* __restrict__ Wex,
                                             const float* __restrict__ bex,
                                             float* __restrict__ mod) {
    int b = blockIdx.x, t = threadIdx.x;
    __shared__ float sm[128], ssh[64];
    sm[t] = feat[b * 128 + t] * spat[b * 128 + t];
    __syncthreads();
    if (t < 64) {
        float acc = bsh[t];
        for (int c = 0; c < 128; ++c) acc += sm[c] * Wsh[c * 64 + t];
        ssh[t] = geluf(acc);
    }
    __syncthreads();
    float acc = bex[t];
    for (int k = 0; k < 64; ++k) acc += ssh[k] * Wex[k * 128 + t];
    mod[b * 128 + t] = sigmf(acc);
}

// ---------- K4b: xprep — xmT = f16(x * mod), transposed [w][ci] with halo slots ----------
__global__ __launch_bounds__(256) void k_xprep(const float* __restrict__ x,
                                               const float* __restrict__ mod) {
    int bid = blockIdx.x;  // b*128 + h
    int h = bid & 127;
    int b = bid >> 7;
    int t = threadIdx.x;
    __shared__ float sx[32][133];

    for (int chunk = 0; chunk < 4; ++chunk) {
        __syncthreads();
        // load 32ci x 128w fp32, apply mod
#pragma unroll
        for (int it = 0; it < 4; ++it) {
            int ci = it * 8 + (t >> 5);
            int w4 = t & 31;
            int cig = chunk * 32 + ci;
            float4 v = *(const float4*)&x[(((size_t)b * 128 + cig) * 128 + h) * 128 + w4 * 4];
            float m = mod[b * 128 + cig];
            sx[ci][w4 * 4 + 0] = v.x * m;
            sx[ci][w4 * 4 + 1] = v.y * m;
            sx[ci][w4 * 4 + 2] = v.z * m;
            sx[ci][w4 * 4 + 3] = v.w * m;
        }
        __syncthreads();
        // pack 16B granules: 130 slots x 4 halves
        f16* dstc = g_xmT + (((size_t)(b * 128 + h)) * 4 + chunk) * 4160;
        for (int g = t; g < 520; g += 256) {
            int s = g >> 2, c8 = g & 3;
            f16x8 o;
            if (s == 0 || s == 129) {
#pragma unroll
                for (int j = 0; j < 8; ++j) o[j] = (f16)0.f;
            } else {
#pragma unroll
                for (int j = 0; j < 8; ++j) o[j] = (f16)sx[c8 * 8 + j][s - 1];
            }
            *(f16x8*)(dstc + s * 32 + c8 * 8) = o;
        }
    }
}

// ---------- K5 (MFMA): conv1 3x3 + sc 1x1 stats ----------
// One block per (b,h); 4 waves in 2x2 (co,w) grid, each wave 64co x 64w via 4x4
// fragments of mfma_f32_16x16x32_f16. x comes pre-transposed/f16 from g_xmT
// (trivial LDS copy), weights read as fragments directly from L2-hot g_Wc/g_Wsc.
__global__ __launch_bounds__(256, 2) void k_conv1m(float* __restrict__ y1,
                                                   float* __restrict__ stats) {
    int bid = blockIdx.x;          // b*128 + h
    int h = bid & 127;
    int b = bid >> 7;
    int t = threadIdx.x;
    int lane = t & 63;
    int wv = t >> 6;
    int l15 = lane & 15, lg = lane >> 4;
    int co_half = (wv >> 1) * 64;
    int w_half = (wv & 1) * 64;

    __shared__ f16 xs[3][130][40];   // 31200 B, 80B slot stride (16B aligned, 2-way banks)

    f32x4 acc[4][4], asc[4][4];
#pragma unroll
    for (int ct = 0; ct < 4; ++ct)
#pragma unroll
        for (int wt = 0; wt < 4; ++wt) {
            acc[ct][wt] = (f32x4){0.f, 0.f, 0.f, 0.f};
            asc[ct][wt] = (f32x4){0.f, 0.f, 0.f, 0.f};
        }

    f16x8 z8;
#pragma unroll
    for (int j = 0; j < 8; ++j) z8[j] = (f16)0.f;

    for (int chunk = 0; chunk < 4; ++chunk) {
        __syncthreads();  // previous chunk reads done
        // stage 3 rows x 130 slots x 32 ci (f16 granules straight from g_xmT)
        for (int g = t; g < 1560; g += 256) {
            int r = g / 520;
            int q = g - r * 520;
            int s = q >> 2, c8 = q & 3;
            int hr = h + r - 1;
            f16x8 v = z8;
            if ((unsigned)hr < 128u)
                v = *(const f16x8*)(g_xmT + (((size_t)(b * 128 + hr)) * 4 + chunk) * 4160 + s * 32 + c8 * 8);
            *(f16x8*)&xs[r][s][c8 * 8] = v;
        }
        __syncthreads();

#pragma unroll
        for (int tap = 0; tap < 9; ++tap) {
            const int kh = tap / 3, kw = tap - kh * 3;
            f16x8 af[4], bf[4];
#pragma unroll
            for (int ct = 0; ct < 4; ++ct)
                af[ct] = *(const f16x8*)(g_Wc + ((size_t)(tap * 4 + chunk) * 128 + co_half + ct * 16 + l15) * 32 + lg * 8);
#pragma unroll
            for (int wt = 0; wt < 4; ++wt)
                bf[wt] = *(const f16x8*)&xs[kh][w_half + wt * 16 + l15 + kw][lg * 8];
#pragma unroll
            for (int ct = 0; ct < 4; ++ct)
#pragma unroll
                for (int wt = 0; wt < 4; ++wt)
                    acc[ct][wt] = __builtin_amdgcn_mfma_f32_16x16x32_f16(
                        af[ct], bf[wt], acc[ct][wt], 0, 0, 0);

            if (tap == 4) {  // center tap: same B frags feed the 1x1 shortcut stats
                f16x8 sf[4];
#pragma unroll
                for (int ct = 0; ct < 4; ++ct)
                    sf[ct] = *(const f16x8*)(g_Wsc + ((size_t)chunk * 128 + co_half + ct * 16 + l15) * 32 + lg * 8);
#pragma unroll
                for (int ct = 0; ct < 4; ++ct)
#pragma unroll
                    for (int wt = 0; wt < 4; ++wt)
                        asc[ct][wt] = __builtin_amdgcn_mfma_f32_16x16x32_f16(
                            sf[ct], bf[wt], asc[ct][wt], 0, 0, 0);
            }
        }
    }

    // ---- epilogue: write y1 (fp32) + bn1/bnsc stats ----
    float* yb = y1 + (size_t)b * 128 * PLANE + (size_t)h * 128;
#pragma unroll
    for (int ct = 0; ct < 4; ++ct) {
#pragma unroll
        for (int r = 0; r < 4; ++r) {
            int co = co_half + ct * 16 + lg * 4 + r;
            float s = 0, q = 0, ss = 0, qq = 0;
#pragma unroll
            for (int wt = 0; wt < 4; ++wt) {
                float v = acc[ct][wt][r];
                yb[(size_t)co * PLANE + w_half + wt * 16 + l15] = v;
                s += v; q += v * v;
                float u = asc[ct][wt][r];
                ss += u; qq += u * u;
            }
#pragma unroll
            for (int o = 1; o < 16; o <<= 1) {
                s += __shfl_xor(s, o);
                q += __shfl_xor(q, o);
                ss += __shfl_xor(ss, o);
                qq += __shfl_xor(qq, o);
            }
            if (l15 == 0) {
                atomicAdd(&stats[co], s);
                atomicAdd(&stats[128 + co], q);
                atomicAdd(&stats[256 + co], ss);
                atomicAdd(&stats[384 + co], qq);
            }
        }
    }
}

// ---------- K6: finalize bn1 + bnsc -> affine coefs ----------
__global__ __launch_bounds__(256) void k_fin1(const float* __restrict__ stats,
                                              const float* __restrict__ g1, const float* __restrict__ be1,
                                              const float* __restrict__ gsc, const float* __restrict__ bsc,
                                              float* __restrict__ coef) {
    int t = threadIdx.x;
    const float inv = 1.0f / NSTAT;
    if (t < 128) {
        float m = stats[t] * inv;
        float v = stats[128 + t] * inv - m * m;
        float a = g1[t] * rsqrtf(v + 1e-5f);
        coef[t] = a;
        coef[128 + t] = be1[t] - m * a;
    } else {
        int c = t - 128;
        float m = stats[256 + c] * inv;
        float v = stats[384 + c] * inv - m * m;
        float a = gsc[c] * rsqrtf(v + 1e-5f);
        coef[256 + c] = a;
        coef[384 + c] = bsc[c] - m * a;
    }
}

// ---------- K7 (MFMA): conv2 (1x1) over bb=silu(bn1(y1)) -> bn2 stats only ----------
__global__ __launch_bounds__(256, 2) void k_conv2m(const float* __restrict__ y1,
                                                   const float* __restrict__ coef,
                                                   float* __restrict__ stats) {
    int bid = blockIdx.x;          // b*128 + h
    int h = bid & 127;
    int b = bid >> 7;
    int t = threadIdx.x;
    int lane = t & 63;
    int wv = t >> 6;
    int l15 = lane & 15, lg = lane >> 4;
    int co_half = (wv >> 1) * 64;
    int w_half = (wv & 1) * 64;

    __shared__ float sy[32][133];
    __shared__ f16 bbs[128][40];

    f32x4 acc[4][4];
#pragma unroll
    for (int ct = 0; ct < 4; ++ct)
#pragma unroll
        for (int wt = 0; wt < 4; ++wt) acc[ct][wt] = (f32x4){0.f, 0.f, 0.f, 0.f};

    for (int chunk = 0; chunk < 4; ++chunk) {
        __syncthreads();
        // load y1 chunk + bn1 affine + silu
#pragma unroll
        for (int it = 0; it < 4; ++it) {
            int ci = it * 8 + (t >> 5);
            int w4 = t & 31;
            int cig = chunk * 32 + ci;
            float a = coef[cig], c = coef[128 + cig];
            float4 v = *(const float4*)&y1[(((size_t)b * 128 + cig) * 128 + h) * 128 + w4 * 4];
            float u0 = a * v.x + c; u0 = u0 * sigmf(u0);
            float u1 = a * v.y + c; u1 = u1 * sigmf(u1);
            float u2 = a * v.z + c; u2 = u2 * sigmf(u2);
            float u3 = a * v.w + c; u3 = u3 * sigmf(u3);
            sy[ci][w4 * 4 + 0] = u0;
            sy[ci][w4 * 4 + 1] = u1;
            sy[ci][w4 * 4 + 2] = u2;
            sy[ci][w4 * 4 + 3] = u3;
        }
        __syncthreads();
        // pack transposed f16 granules
        for (int g = t; g < 512; g += 256) {
            int s = g >> 2, c8 = g & 3;
            f16x8 o;
#pragma unroll
            for (int j = 0; j < 8; ++j) o[j] = (f16)sy[c8 * 8 + j][s];
            *(f16x8*)&bbs[s][c8 * 8] = o;
        }
        __syncthreads();
        // MFMA
        f16x8 af[4], bf[4];
#pragma unroll
        for (int ct = 0; ct < 4; ++ct)
            af[ct] = *(const f16x8*)(g_W2 + ((size_t)chunk * 128 + co_half + ct * 16 + l15) * 32 + lg * 8);
#pragma unroll
        for (int wt = 0; wt < 4; ++wt)
            bf[wt] = *(const f16x8*)&bbs[w_half + wt * 16 + l15][lg * 8];
#pragma unroll
        for (int ct = 0; ct < 4; ++ct)
#pragma unroll
            for (int wt = 0; wt < 4; ++wt)
                acc[ct][wt] = __builtin_amdgcn_mfma_f32_16x16x32_f16(
                    af[ct], bf[wt], acc[ct][wt], 0, 0, 0);
    }

    // stats epilogue
#pragma unroll
    for (int ct = 0; ct < 4; ++ct) {
#pragma unroll
        for (int r = 0; r < 4; ++r) {
            int co = co_half + ct * 16 + lg * 4 + r;
            float s = 0, q = 0;
#pragma unroll
            for (int wt = 0; wt < 4; ++wt) {
                float v = acc[ct][wt][r];
                s += v; q += v * v;
            }
#pragma unroll
            for (int o = 1; o < 16; o <<= 1) {
                s += __shfl_xor(s, o);
                q += __shfl_xor(q, o);
            }
            if (l15 == 0) {
                atomicAdd(&stats[512 + co], s);
                atomicAdd(&stats[640 + co], q);
            }
        }
    }
}

// ---------- K8: finalize bn2 ----------
__global__ __launch_bounds__(128) void k_fin2(const float* __restrict__ stats,
                                              const float* __restrict__ g2, const float* __restrict__ be2,
                                              float* __restrict__ coef) {
    int c = threadIdx.x;
    const float inv = 1.0f / NSTAT;
    float m = stats[512 + c] * inv;
    float v = stats[640 + c] * inv - m * m;
    float a = g2[c] * rsqrtf(v + 1e-5f);
    coef[512 + c] = a;
    coef[640 + c] = be2[c] - m * a;
}

// ---------- K9 (MFMA): out = silu(bn2(conv2(bb)) + bnsc(sc(xm))) ----------
// Slice-local 1x1 convs: block (b,h) reads only y1(b,:,h,:) and overwrites only
// out(b,:,h,:) — all y1 reads precede all writes (writes are epilogue-only).
__global__ __launch_bounds__(256, 2) void k_final(float* __restrict__ yio,
                                                  const float* __restrict__ coef) {
    int bid = blockIdx.x;          // b*128 + h
    int h = bid & 127;
    int b = bid >> 7;
    int t = threadIdx.x;
    int lane = t & 63;
    int wv = t >> 6;
    int l15 = lane & 15, lg = lane >> 4;
    int co_half = (wv >> 1) * 64;
    int w_half = (wv & 1) * 64;

    __shared__ float sy[32][133];
    __shared__ f16 bbs[128][40];

    f32x4 acc[4][4], asc[4][4];
#pragma unroll
    for (int ct = 0; ct < 4; ++ct)
#pragma unroll
        for (int wt = 0; wt < 4; ++wt) {
            acc[ct][wt] = (f32x4){0.f, 0.f, 0.f, 0.f};
            asc[ct][wt] = (f32x4){0.f, 0.f, 0.f, 0.f};
        }

    for (int chunk = 0; chunk < 4; ++chunk) {
        __syncthreads();
#pragma unroll
        for (int it = 0; it < 4; ++it) {
            int ci = it * 8 + (t >> 5);
            int w4 = t & 31;
            int cig = chunk * 32 + ci;
            float a = coef[cig], c = coef[128 + cig];
            float4 v = *(const float4*)&yio[(((size_t)b * 128 + cig) * 128 + h) * 128 + w4 * 4];
            float u0 = a * v.x + c; u0 = u0 * sigmf(u0);
            float u1 = a * v.y + c; u1 = u1 * sigmf(u1);
            float u2 = a * v.z + c; u2 = u2 * sigmf(u2);
            float u3 = a * v.w + c; u3 = u3 * sigmf(u3);
            sy[ci][w4 * 4 + 0] = u0;
            sy[ci][w4 * 4 + 1] = u1;
            sy[ci][w4 * 4 + 2] = u2;
            sy[ci][w4 * 4 + 3] = u3;
        }
        __syncthreads();
        for (int g = t; g < 512; g += 256) {
            int s = g >> 2, c8 = g & 3;
            f16x8 o;
#pragma unroll
            for (int j = 0; j < 8; ++j) o[j] = (f16)sy[c8 * 8 + j][s];
            *(f16x8*)&bbs[s][c8 * 8] = o;
        }
        __syncthreads();

        f16x8 af[4], sf[4], bf[4], bx[4];
#pragma unroll
        for (int ct = 0; ct < 4; ++ct) {
            af[ct] = *(const f16x8*)(g_W2 + ((size_t)chunk * 128 + co_half + ct * 16 + l15) * 32 + lg * 8);
            sf[ct] = *(const f16x8*)(g_Wsc + ((size_t)chunk * 128 + co_half + ct * 16 + l15) * 32 + lg * 8);
        }
#pragma unroll
        for (int wt = 0; wt < 4; ++wt) {
            bf[wt] = *(const f16x8*)&bbs[w_half + wt * 16 + l15][lg * 8];
            bx[wt] = *(const f16x8*)(g_xmT + (((size_t)(b * 128 + h)) * 4 + chunk) * 4160
                                     + (w_half + wt * 16 + l15 + 1) * 32 + lg * 8);
        }
#pragma unroll
        for (int ct = 0; ct < 4; ++ct)
#pragma unroll
            for (int wt = 0; wt < 4; ++wt) {
                acc[ct][wt] = __builtin_amdgcn_mfma_f32_16x16x32_f16(
                    af[ct], bf[wt], acc[ct][wt], 0, 0, 0);
                asc[ct][wt] = __builtin_amdgcn_mfma_f32_16x16x32_f16(
                    sf[ct], bx[wt], asc[ct][wt], 0, 0, 0);
            }
    }

    // epilogue: combine + silu + overwrite own slice
#pragma unroll
    for (int ct = 0; ct < 4; ++ct) {
#pragma unroll
        for (int r = 0; r < 4; ++r) {
            int co = co_half + ct * 16 + lg * 4 + r;
            float a2 = coef[512 + co], c2 = coef[640 + co];
            float as = coef[256 + co], cs = coef[384 + co];
#pragma unroll
            for (int wt = 0; wt < 4; ++wt) {
                float v = a2 * acc[ct][wt][r] + c2 + as * asc[ct][wt][r] + cs;
                v = v * sigmf(v);
                yio[(((size_t)b * 128 + co) * 128 + h) * 128 + w_half + wt * 16 + l15] = v;
            }
        }
    }
}

// ---------- launcher ----------
extern "C" void kernel_launch(void* const* d_in, const int* in_sizes, int n_in,
                              void* d_out, int out_size, void* d_ws, size_t ws_size,
                              hipStream_t stream) {
    (void)in_sizes; (void)n_in; (void)out_size; (void)ws_size;
    const float* x    = (const float*)d_in[0];
    const float* dce  = (const float*)d_in[1];
    const float* dwc  = (const float*)d_in[2];
    const float* W1   = (const float*)d_in[3];
    const float* b1   = (const float*)d_in[4];
    const float* W2d  = (const float*)d_in[5];
    const float* b2d  = (const float*)d_in[6];
    const float* Wsh  = (const float*)d_in[7];
    const float* bsh  = (const float*)d_in[8];
    const float* Wex  = (const float*)d_in[9];
    const float* bex  = (const float*)d_in[10];
    const float* c1w  = (const float*)d_in[11];
    const float* g1   = (const float*)d_in[12];
    const float* be1  = (const float*)d_in[13];
    const float* c2w  = (const float*)d_in[14];
    const float* g2   = (const float*)d_in[15];
    const float* be2  = (const float*)d_in[16];
    const float* scw  = (const float*)d_in[17];
    const float* gsc  = (const float*)d_in[18];
    const float* bsc  = (const float*)d_in[19];

    // small float scratch at start of d_ws — y1 lives in d_out (fp32)
    float* F = (float*)d_ws;
    float* dh    = F;            // 2048
    float* feat  = F + 2048;     // 2048
    float* spat  = F + 4096;     // 2048
    float* md    = F + 6144;     // 2048
    float* stats = F + 8192;     // 768
    float* coef  = F + 8960;     // 768

    float* y1 = (float*)d_out;   // conv1 output staged in d_out, overwritten by k_final

    hipMemsetAsync(stats, 0, 768 * sizeof(float), stream);

    k_wprep<<<704, 256, 0, stream>>>(c1w, scw, c2w);
    k_dce1<<<16, 256, 0, stream>>>(dce, W1, b1, dh);
    k_dce2<<<16, 128, 0, stream>>>(dh, W2d, b2d, feat);
    k_spatial<<<2048, 256, 0, stream>>>(x, dwc, spat);
    k_mod<<<16, 128, 0, stream>>>(feat, spat, Wsh, bsh, Wex, bex, md);
    k_xprep<<<2048, 256, 0, stream>>>(x, md);
    k_conv1m<<<2048, 256, 0, stream>>>(y1, stats);
    k_fin1<<<1, 256, 0, stream>>>(stats, g1, be1, gsc, bsc, coef);
    k_conv2m<<<2048, 256, 0, stream>>>(y1, coef, stats);
    k_fin2<<<1, 128, 0, stream>>>(stats, g2, be2, coef);
    k_final<<<2048, 256, 0, stream>>>(y1, coef);
}

// Round 3
// 1346.050 us; speedup vs baseline: 2.3568x; 1.1349x over previous
//
#include <hip/hip_runtime.h>
#include <hip/hip_bf16.h>

typedef _Float16 f16;
typedef __attribute__((ext_vector_type(8))) _Float16 f16x8;
typedef __attribute__((ext_vector_type(4))) _Float16 f16x4;
typedef __attribute__((ext_vector_type(4))) float f32x4;

// ---------- small device helpers ----------
__device__ __forceinline__ float geluf(float x) {
    return 0.5f * x * (1.0f + erff(x * 0.70710678118654752440f));
}
__device__ __forceinline__ float sigmf(float x) { return 1.0f / (1.0f + __expf(-x)); }

// Sizes (fixed by the problem)
#define NB 16
#define NC 128
#define NH 128
#define NW 128
#define PLANE (NH * NW)          // 16384
#define NSTAT 262144.0f          // B*H*W per-channel BN count

// f16 weights / staged tensors in device-global memory (no workspace assumptions).
// g_Wc  : [tap(9)][chunk(4)][co(128)][ci32]
// g_Wsc : [chunk(4)][co(128)][ci32]
// g_W2  : [chunk(4)][co(128)][ci32]
// g_xmT : [b][h][chunk(4)][wslot(130)][ci32]   (slot = w+1; slots 0,129 zero)
// g_y1T : [b][h][cog(4)][w(128)][co32]          (conv1 out, f16)
// g_bbT : [b][h][chunk(4)][w(128)][ci32]        (silu(bn1(y1)), f16)
__device__ __align__(16) f16 g_Wc[9 * 4 * 128 * 32];
__device__ __align__(16) f16 g_Wsc[4 * 128 * 32];
__device__ __align__(16) f16 g_W2[4 * 128 * 32];
__device__ __align__(16) f16 g_xmT[(size_t)16 * 128 * 4 * 130 * 32];
__device__ __align__(16) f16 g_y1T[(size_t)16 * 128 * 4 * 128 * 32];
__device__ __align__(16) f16 g_bbT[(size_t)16 * 128 * 4 * 128 * 32];

// ---------- K0: convert conv1/sc/conv2 weights to f16 in MFMA-friendly layout ----------
__global__ __launch_bounds__(256) void k_wprep(const float* __restrict__ c1w,
                                               const float* __restrict__ scw,
                                               const float* __restrict__ c2w) {
    int i = blockIdx.x * 256 + threadIdx.x;
    if (i < 147456) {                       // 9*4*128*32
        int tap = i / 16384;
        int rem = i - tap * 16384;
        int chunk = rem >> 12;
        int r2 = rem & 4095;
        int co = r2 >> 5;
        int cil = r2 & 31;
        int ci = chunk * 32 + cil;
        g_Wc[i] = (f16)c1w[((size_t)co * 128 + ci) * 9 + tap];
    } else if (i < 163840) {                // + 4*128*32
        int j = i - 147456;
        int chunk = j >> 12;
        int r2 = j & 4095;
        int co = r2 >> 5;
        int cil = r2 & 31;
        g_Wsc[j] = (f16)scw[(size_t)co * 128 + chunk * 32 + cil];
    } else if (i < 180224) {                // + 4*128*32
        int j = i - 163840;
        int chunk = j >> 12;
        int r2 = j & 4095;
        int co = r2 >> 5;
        int cil = j & 31;
        g_W2[j] = (f16)c2w[(size_t)co * 128 + chunk * 32 + cil];
    }
}

// ---------- K1: partial dce @ W1, K-split over 64 blocks, atomicAdd into dh ----------
__global__ __launch_bounds__(256) void k_dce1(const float* __restrict__ dce,
                                              const float* __restrict__ W1,
                                              float* __restrict__ dh) {
    int ks = blockIdx.x;          // 64 slices of 200 k
    int kbase = ks * 200;
    int t = threadIdx.x;
    __shared__ float sdce[16][256];
    for (int e = t; e < 4096; e += 256) {
        int bb = e >> 8, k = e & 255;
        if (k < 200) sdce[bb][k] = dce[(size_t)bb * 12800 + kbase + k];
    }
    __syncthreads();
    int j = t & 127;
    int bg = t >> 7;              // 0/1 -> b 0..7 / 8..15
    float accs[8];
#pragma unroll
    for (int i = 0; i < 8; ++i) accs[i] = 0.0f;
    for (int k = 0; k < 200; ++k) {
        float wv = W1[((size_t)(kbase + k)) * 128 + j];
#pragma unroll
        for (int bb = 0; bb < 8; ++bb) accs[bb] += sdce[bg * 8 + bb][k] * wv;
    }
#pragma unroll
    for (int bb = 0; bb < 8; ++bb)
        atomicAdd(&dh[(bg * 8 + bb) * 128 + j], accs[bb]);
}

// ---------- K2: dce_feat = gelu(dh + b1) @ W2 + b2, [16,128] ----------
__global__ __launch_bounds__(128) void k_dce2(const float* __restrict__ dh,
                                              const float* __restrict__ b1,
                                              const float* __restrict__ W2,
                                              const float* __restrict__ b2,
                                              float* __restrict__ feat) {
    int b = blockIdx.x, j = threadIdx.x;
    __shared__ float sh[128];
    sh[j] = geluf(dh[b * 128 + j] + b1[j]);
    __syncthreads();
    float acc = b2[j];
    for (int k = 0; k < 128; ++k) acc += sh[k] * W2[k * 128 + j];
    feat[b * 128 + j] = acc;
}

// ---------- K3: spatial features via border-corrected sums (shuffle reduce) ----------
__global__ __launch_bounds__(256) void k_spatial(const float* __restrict__ x,
                                                 const float* __restrict__ dw,
                                                 float* __restrict__ spat) {
    int bc = blockIdx.x;  // b*128+c
    int t = threadIdx.x;
    const float* p = x + (size_t)bc * PLANE;
    float f = 0, r0 = 0, r1 = 0, c0 = 0, c1 = 0;
    for (int i = t; i < PLANE; i += 256) {
        float v = p[i];
        int row = i >> 7, col = i & 127;
        f += v;
        if (row == 0) r0 += v;
        if (row == 127) r1 += v;
        if (col == 0) c0 += v;
        if (col == 127) c1 += v;
    }
#pragma unroll
    for (int o = 1; o < 64; o <<= 1) {
        f  += __shfl_xor(f, o);
        r0 += __shfl_xor(r0, o);
        r1 += __shfl_xor(r1, o);
        c0 += __shfl_xor(c0, o);
        c1 += __shfl_xor(c1, o);
    }
    __shared__ float wr[4][5];
    int wid = t >> 6;
    if ((t & 63) == 0) {
        wr[wid][0] = f; wr[wid][1] = r0; wr[wid][2] = r1; wr[wid][3] = c0; wr[wid][4] = c1;
    }
    __syncthreads();
    if (t == 0) {
        float full = 0, row0 = 0, row127 = 0, col0 = 0, col127 = 0;
#pragma unroll
        for (int w = 0; w < 4; ++w) {
            full += wr[w][0]; row0 += wr[w][1]; row127 += wr[w][2];
            col0 += wr[w][3]; col127 += wr[w][4];
        }
        int c = bc & 127;
        float x00 = p[0];
        float x0e = p[127];
        float xe0 = p[127 * 128];
        float xee = p[127 * 128 + 127];
        float acc = 0.0f;
        for (int kh = 0; kh < 3; ++kh)
            for (int kw = 0; kw < 3; ++kw) {
                int dh_ = kh - 1, dwv = kw - 1;
                float T = full;
                if (dh_ == -1) T -= row127;
                else if (dh_ == 1) T -= row0;
                if (dwv == -1) T -= col127;
                else if (dwv == 1) T -= col0;
                if (dh_ == -1 && dwv == -1) T += xee;
                if (dh_ == -1 && dwv == 1) T += xe0;
                if (dh_ == 1 && dwv == -1) T += x0e;
                if (dh_ == 1 && dwv == 1) T += x00;
                acc += dw[c * 9 + kh * 3 + kw] * T;
            }
        spat[bc] = acc * (1.0f / 16384.0f);
    }
}

// ---------- K4: SE modulation -> mod_w [16,128] ----------
__global__ __launch_bounds__(128) void k_mod(const float* __restrict__ feat,
                                             const float* __restrict__ spat,
                                             const float* __restrict__ Wsh,
                                             const float* __restrict__ bsh,
                                             const float* __restrict__ Wex,
                                             const float* __restrict__ bex,
                                             float* __restrict__ mod) {
    int b = blockIdx.x, t = threadIdx.x;
    __shared__ float sm[128], ssh[64];
    sm[t] = feat[b * 128 + t] * spat[b * 128 + t];
    __syncthreads();
    if (t < 64) {
        float acc = bsh[t];
        for (int c = 0; c < 128; ++c) acc += sm[c] * Wsh[c * 64 + t];
        ssh[t] = geluf(acc);
    }
    __syncthreads();
    float acc = bex[t];
    for (int k = 0; k < 64; ++k) acc += ssh[k] * Wex[k * 128 + t];
    mod[b * 128 + t] = sigmf(acc);
}

// ---------- K4b: xprep — xmT = f16(x * mod), transposed [w][ci] with halo slots ----------
__global__ __launch_bounds__(256) void k_xprep(const float* __restrict__ x,
                                               const float* __restrict__ mod) {
    int bid = blockIdx.x;  // b*128 + h
    int h = bid & 127;
    int b = bid >> 7;
    int t = threadIdx.x;
    __shared__ float sx[32][133];

    for (int chunk = 0; chunk < 4; ++chunk) {
        __syncthreads();
#pragma unroll
        for (int it = 0; it < 4; ++it) {
            int ci = it * 8 + (t >> 5);
            int w4 = t & 31;
            int cig = chunk * 32 + ci;
            float4 v = *(const float4*)&x[(((size_t)b * 128 + cig) * 128 + h) * 128 + w4 * 4];
            float m = mod[b * 128 + cig];
            sx[ci][w4 * 4 + 0] = v.x * m;
            sx[ci][w4 * 4 + 1] = v.y * m;
            sx[ci][w4 * 4 + 2] = v.z * m;
            sx[ci][w4 * 4 + 3] = v.w * m;
        }
        __syncthreads();
        f16* dstc = g_xmT + (((size_t)(b * 128 + h)) * 4 + chunk) * 4160;
        for (int g = t; g < 520; g += 256) {
            int s = g >> 2, c8 = g & 3;
            f16x8 o;
            if (s == 0 || s == 129) {
#pragma unroll
                for (int j = 0; j < 8; ++j) o[j] = (f16)0.f;
            } else {
#pragma unroll
                for (int j = 0; j < 8; ++j) o[j] = (f16)sx[c8 * 8 + j][s - 1];
            }
            *(f16x8*)(dstc + s * 32 + c8 * 8) = o;
        }
    }
}

// ---------- K5 (MFMA): conv1 3x3 -> y1T f16 + bn1 stats ----------
// XCD-swizzled (b,h) blocks; T14 async-stage: next chunk's global loads issued
// before the 144-MFMA compute phase, LDS-written after the barrier.
__global__ __launch_bounds__(256, 2) void k_conv1m(float* __restrict__ stats) {
    int orig = blockIdx.x;
    int sw = (orig & 7) * 256 + (orig >> 3);   // bijective: 2048 % 8 == 0
    int h = sw & 127;
    int b = sw >> 7;
    int t = threadIdx.x;
    int lane = t & 63;
    int wv = t >> 6;
    int l15 = lane & 15, lg = lane >> 4;
    int co_half = (wv >> 1) * 64;
    int w_half = (wv & 1) * 64;

    __shared__ f16 xs[3][130][40];   // 31200 B

    f32x4 acc[4][4];
#pragma unroll
    for (int ct = 0; ct < 4; ++ct)
#pragma unroll
        for (int wt = 0; wt < 4; ++wt) acc[ct][wt] = (f32x4){0.f, 0.f, 0.f, 0.f};

    f16x8 z8;
#pragma unroll
    for (int j = 0; j < 8; ++j) z8[j] = (f16)0.f;

    f16x8 st[7];

    // prologue: stage chunk 0
#pragma unroll
    for (int i = 0; i < 7; ++i) {
        int g = t + i * 256;
        if (g < 1560) {
            int r = g / 520;
            int q = g - r * 520;
            int s = q >> 2, c8 = q & 3;
            int hr = h + r - 1;
            st[i] = z8;
            if ((unsigned)hr < 128u)
                st[i] = *(const f16x8*)(g_xmT + (((size_t)(b * 128 + hr)) * 4 + 0) * 4160 + s * 32 + c8 * 8);
        }
    }
#pragma unroll
    for (int i = 0; i < 7; ++i) {
        int g = t + i * 256;
        if (g < 1560) {
            int r = g / 520;
            int q = g - r * 520;
            *(f16x8*)&xs[r][q >> 2][(q & 3) * 8] = st[i];
        }
    }
    __syncthreads();

    for (int chunk = 0; chunk < 4; ++chunk) {
        // issue next chunk's loads (stay in flight under the MFMA phase)
        if (chunk < 3) {
#pragma unroll
            for (int i = 0; i < 7; ++i) {
                int g = t + i * 256;
                if (g < 1560) {
                    int r = g / 520;
                    int q = g - r * 520;
                    int s = q >> 2, c8 = q & 3;
                    int hr = h + r - 1;
                    st[i] = z8;
                    if ((unsigned)hr < 128u)
                        st[i] = *(const f16x8*)(g_xmT + (((size_t)(b * 128 + hr)) * 4 + chunk + 1) * 4160 + s * 32 + c8 * 8);
                }
            }
        }

#pragma unroll
        for (int tap = 0; tap < 9; ++tap) {
            const int kh = tap / 3, kw = tap - kh * 3;
            f16x8 af[4], bf[4];
#pragma unroll
            for (int ct = 0; ct < 4; ++ct)
                af[ct] = *(const f16x8*)(g_Wc + ((size_t)(tap * 4 + chunk) * 128 + co_half + ct * 16 + l15) * 32 + lg * 8);
#pragma unroll
            for (int wt = 0; wt < 4; ++wt)
                bf[wt] = *(const f16x8*)&xs[kh][w_half + wt * 16 + l15 + kw][lg * 8];
#pragma unroll
            for (int ct = 0; ct < 4; ++ct)
#pragma unroll
                for (int wt = 0; wt < 4; ++wt)
                    acc[ct][wt] = __builtin_amdgcn_mfma_f32_16x16x32_f16(
                        af[ct], bf[wt], acc[ct][wt], 0, 0, 0);
        }

        __syncthreads();   // all reads of xs done
        if (chunk < 3) {
#pragma unroll
            for (int i = 0; i < 7; ++i) {
                int g = t + i * 256;
                if (g < 1560) {
                    int r = g / 520;
                    int q = g - r * 520;
                    *(f16x8*)&xs[r][q >> 2][(q & 3) * 8] = st[i];
                }
            }
            __syncthreads();
        }
    }

    // ---- epilogue: write y1T (f16) + bn1 stats ----
#pragma unroll
    for (int ct = 0; ct < 4; ++ct) {
        int cog = (wv >> 1) * 2 + (ct >> 1);
        int col = (ct & 1) * 16 + lg * 4;
#pragma unroll
        for (int wt = 0; wt < 4; ++wt) {
            int w = w_half + wt * 16 + l15;
            f16x4 pk;
            pk[0] = (f16)acc[ct][wt][0];
            pk[1] = (f16)acc[ct][wt][1];
            pk[2] = (f16)acc[ct][wt][2];
            pk[3] = (f16)acc[ct][wt][3];
            *(f16x4*)(g_y1T + ((((size_t)(b * 128 + h)) * 4 + cog) * 128 + w) * 32 + col) = pk;
        }
#pragma unroll
        for (int r = 0; r < 4; ++r) {
            int co = co_half + ct * 16 + lg * 4 + r;
            float s = 0, q = 0;
#pragma unroll
            for (int wt = 0; wt < 4; ++wt) {
                float v = acc[ct][wt][r];
                s += v; q += v * v;
            }
#pragma unroll
            for (int o = 1; o < 16; o <<= 1) {
                s += __shfl_xor(s, o);
                q += __shfl_xor(q, o);
            }
            if (l15 == 0) {
                atomicAdd(&stats[co], s);
                atomicAdd(&stats[128 + co], q);
            }
        }
    }
}

// ---------- K6: finalize bn1 -> affine coefs ----------
__global__ __launch_bounds__(128) void k_fin1(const float* __restrict__ stats,
                                              const float* __restrict__ g1, const float* __restrict__ be1,
                                              float* __restrict__ coef) {
    int t = threadIdx.x;
    const float inv = 1.0f / NSTAT;
    float m = stats[t] * inv;
    float v = stats[128 + t] * inv - m * m;
    float a = g1[t] * rsqrtf(v + 1e-5f);
    coef[t] = a;
    coef[128 + t] = be1[t] - m * a;
}

// ---------- K7 (MFMA): conv2 (1x1) bn2-stats + sc (1x1) stats; writes bbT ----------
// Zero LDS, zero barriers: fragments straight from g_y1T/g_xmT/weights.
__global__ __launch_bounds__(256, 2) void k_conv2m(const float* __restrict__ coef,
                                                   float* __restrict__ stats) {
    int bid = blockIdx.x;          // b*128 + h
    int h = bid & 127;
    int b = bid >> 7;
    int t = threadIdx.x;
    int lane = t & 63;
    int wv = t >> 6;
    int l15 = lane & 15, lg = lane >> 4;
    int co_half = (wv >> 1) * 64;
    int w_half = (wv & 1) * 64;

    f32x4 acc[4][4], asc[4][4];
#pragma unroll
    for (int ct = 0; ct < 4; ++ct)
#pragma unroll
        for (int wt = 0; wt < 4; ++wt) {
            acc[ct][wt] = (f32x4){0.f, 0.f, 0.f, 0.f};
            asc[ct][wt] = (f32x4){0.f, 0.f, 0.f, 0.f};
        }

    for (int chunk = 0; chunk < 4; ++chunk) {
        float ca[8], cc[8];
#pragma unroll
        for (int j = 0; j < 8; ++j) {
            int ci = chunk * 32 + lg * 8 + j;
            ca[j] = coef[ci];
            cc[j] = coef[128 + ci];
        }
        f16x8 bfr[4], bx[4];
#pragma unroll
        for (int wt = 0; wt < 4; ++wt) {
            int w = w_half + wt * 16 + l15;
            f16x8 raw = *(const f16x8*)(g_y1T + ((((size_t)(b * 128 + h)) * 4 + chunk) * 128 + w) * 32 + lg * 8);
#pragma unroll
            for (int j = 0; j < 8; ++j) {
                float v = ca[j] * (float)raw[j] + cc[j];
                bfr[wt][j] = (f16)(v * sigmf(v));
            }
            bx[wt] = *(const f16x8*)(g_xmT + (((size_t)(b * 128 + h)) * 4 + chunk) * 4160 + (w + 1) * 32 + lg * 8);
        }
        if (wv < 2) {   // each w written once
#pragma unroll
            for (int wt = 0; wt < 4; ++wt) {
                int w = w_half + wt * 16 + l15;
                *(f16x8*)(g_bbT + ((((size_t)(b * 128 + h)) * 4 + chunk) * 128 + w) * 32 + lg * 8) = bfr[wt];
            }
        }
        f16x8 af[4], sf[4];
#pragma unroll
        for (int ct = 0; ct < 4; ++ct) {
            af[ct] = *(const f16x8*)(g_W2 + ((size_t)chunk * 128 + co_half + ct * 16 + l15) * 32 + lg * 8);
            sf[ct] = *(const f16x8*)(g_Wsc + ((size_t)chunk * 128 + co_half + ct * 16 + l15) * 32 + lg * 8);
        }
#pragma unroll
        for (int ct = 0; ct < 4; ++ct)
#pragma unroll
            for (int wt = 0; wt < 4; ++wt) {
                acc[ct][wt] = __builtin_amdgcn_mfma_f32_16x16x32_f16(
                    af[ct], bfr[wt], acc[ct][wt], 0, 0, 0);
                asc[ct][wt] = __builtin_amdgcn_mfma_f32_16x16x32_f16(
                    sf[ct], bx[wt], asc[ct][wt], 0, 0, 0);
            }
    }

    // stats: conv2 -> [512],[640]; sc -> [256],[384]
#pragma unroll
    for (int ct = 0; ct < 4; ++ct) {
#pragma unroll
        for (int r = 0; r < 4; ++r) {
            int co = co_half + ct * 16 + lg * 4 + r;
            float s = 0, q = 0, ss = 0, qq = 0;
#pragma unroll
            for (int wt = 0; wt < 4; ++wt) {
                float v = acc[ct][wt][r];
                s += v; q += v * v;
                float u = asc[ct][wt][r];
                ss += u; qq += u * u;
            }
#pragma unroll
            for (int o = 1; o < 16; o <<= 1) {
                s += __shfl_xor(s, o);
                q += __shfl_xor(q, o);
                ss += __shfl_xor(ss, o);
                qq += __shfl_xor(qq, o);
            }
            if (l15 == 0) {
                atomicAdd(&stats[512 + co], s);
                atomicAdd(&stats[640 + co], q);
                atomicAdd(&stats[256 + co], ss);
                atomicAdd(&stats[384 + co], qq);
            }
        }
    }
}

// ---------- K8: finalize bn2 + bnsc ----------
__global__ __launch_bounds__(256) void k_fin2(const float* __restrict__ stats,
                                              const float* __restrict__ g2, const float* __restrict__ be2,
                                              const float* __restrict__ gsc, const float* __restrict__ bsc,
                                              float* __restrict__ coef) {
    int t = threadIdx.x;
    const float inv = 1.0f / NSTAT;
    if (t < 128) {
        float m = stats[512 + t] * inv;
        float v = stats[640 + t] * inv - m * m;
        float a = g2[t] * rsqrtf(v + 1e-5f);
        coef[512 + t] = a;
        coef[640 + t] = be2[t] - m * a;
    } else {
        int c = t - 128;
        float m = stats[256 + c] * inv;
        float v = stats[384 + c] * inv - m * m;
        float a = gsc[c] * rsqrtf(v + 1e-5f);
        coef[256 + c] = a;
        coef[384 + c] = bsc[c] - m * a;
    }
}

// ---------- K9 (MFMA): out = silu(bn2(conv2(bb)) + bnsc(sc(xm))) ----------
// Zero LDS; reads g_bbT + g_xmT fragments; writes d_out only.
__global__ __launch_bounds__(256, 2) void k_final(float* __restrict__ out,
                                                  const float* __restrict__ coef) {
    int bid = blockIdx.x;          // b*128 + h
    int h = bid & 127;
    int b = bid >> 7;
    int t = threadIdx.x;
    int lane = t & 63;
    int wv = t >> 6;
    int l15 = lane & 15, lg = lane >> 4;
    int co_half = (wv >> 1) * 64;
    int w_half = (wv & 1) * 64;

    f32x4 acc[4][4], asc[4][4];
#pragma unroll
    for (int ct = 0; ct < 4; ++ct)
#pragma unroll
        for (int wt = 0; wt < 4; ++wt) {
            acc[ct][wt] = (f32x4){0.f, 0.f, 0.f, 0.f};
            asc[ct][wt] = (f32x4){0.f, 0.f, 0.f, 0.f};
        }

    for (int chunk = 0; chunk < 4; ++chunk) {
        f16x8 bf[4], bx[4], af[4], sf[4];
#pragma unroll
        for (int wt = 0; wt < 4; ++wt) {
            int w = w_half + wt * 16 + l15;
            bf[wt] = *(const f16x8*)(g_bbT + ((((size_t)(b * 128 + h)) * 4 + chunk) * 128 + w) * 32 + lg * 8);
            bx[wt] = *(const f16x8*)(g_xmT + (((size_t)(b * 128 + h)) * 4 + chunk) * 4160 + (w + 1) * 32 + lg * 8);
        }
#pragma unroll
        for (int ct = 0; ct < 4; ++ct) {
            af[ct] = *(const f16x8*)(g_W2 + ((size_t)chunk * 128 + co_half + ct * 16 + l15) * 32 + lg * 8);
            sf[ct] = *(const f16x8*)(g_Wsc + ((size_t)chunk * 128 + co_half + ct * 16 + l15) * 32 + lg * 8);
        }
#pragma unroll
        for (int ct = 0; ct < 4; ++ct)
#pragma unroll
            for (int wt = 0; wt < 4; ++wt) {
                acc[ct][wt] = __builtin_amdgcn_mfma_f32_16x16x32_f16(
                    af[ct], bf[wt], acc[ct][wt], 0, 0, 0);
                asc[ct][wt] = __builtin_amdgcn_mfma_f32_16x16x32_f16(
                    sf[ct], bx[wt], asc[ct][wt], 0, 0, 0);
            }
    }

    // epilogue: combine + silu + store
#pragma unroll
    for (int ct = 0; ct < 4; ++ct) {
#pragma unroll
        for (int r = 0; r < 4; ++r) {
            int co = co_half + ct * 16 + lg * 4 + r;
            float a2 = coef[512 + co], c2 = coef[640 + co];
            float as = coef[256 + co], cs = coef[384 + co];
#pragma unroll
            for (int wt = 0; wt < 4; ++wt) {
                float v = a2 * acc[ct][wt][r] + c2 + as * asc[ct][wt][r] + cs;
                v = v * sigmf(v);
                out[(((size_t)b * 128 + co) * 128 + h) * 128 + w_half + wt * 16 + l15] = v;
            }
        }
    }
}

// ---------- launcher ----------
extern "C" void kernel_launch(void* const* d_in, const int* in_sizes, int n_in,
                              void* d_out, int out_size, void* d_ws, size_t ws_size,
                              hipStream_t stream) {
    (void)in_sizes; (void)n_in; (void)out_size; (void)ws_size;
    const float* x    = (const float*)d_in[0];
    const float* dce  = (const float*)d_in[1];
    const float* dwc  = (const float*)d_in[2];
    const float* W1   = (const float*)d_in[3];
    const float* b1   = (const float*)d_in[4];
    const float* W2d  = (const float*)d_in[5];
    const float* b2d  = (const float*)d_in[6];
    const float* Wsh  = (const float*)d_in[7];
    const float* bsh  = (const float*)d_in[8];
    const float* Wex  = (const float*)d_in[9];
    const float* bex  = (const float*)d_in[10];
    const float* c1w  = (const float*)d_in[11];
    const float* g1   = (const float*)d_in[12];
    const float* be1  = (const float*)d_in[13];
    const float* c2w  = (const float*)d_in[14];
    const float* g2   = (const float*)d_in[15];
    const float* be2  = (const float*)d_in[16];
    const float* scw  = (const float*)d_in[17];
    const float* gsc  = (const float*)d_in[18];
    const float* bsc  = (const float*)d_in[19];

    // scratch layout in d_ws (floats):
    // [0..2048) dh  [2048..2816) stats  [2816..3584) coef
    // [3584..5632) feat  [5632..7680) spat  [7680..9728) md
    float* F = (float*)d_ws;
    float* dh    = F;
    float* stats = F + 2048;
    float* coef  = F + 2816;
    float* feat  = F + 3584;
    float* spat  = F + 5632;
    float* md    = F + 7680;

    float* out = (float*)d_out;

    hipMemsetAsync(F, 0, (2048 + 768) * sizeof(float), stream);  // dh + stats

    k_wprep<<<704, 256, 0, stream>>>(c1w, scw, c2w);
    k_dce1<<<64, 256, 0, stream>>>(dce, W1, dh);
    k_dce2<<<16, 128, 0, stream>>>(dh, b1, W2d, b2d, feat);
    k_spatial<<<2048, 256, 0, stream>>>(x, dwc, spat);
    k_mod<<<16, 128, 0, stream>>>(feat, spat, Wsh, bsh, Wex, bex, md);
    k_xprep<<<2048, 256, 0, stream>>>(x, md);
    k_conv1m<<<2048, 256, 0, stream>>>(stats);
    k_fin1<<<1, 128, 0, stream>>>(stats, g1, be1, coef);
    k_conv2m<<<2048, 256, 0, stream>>>(coef, stats);
    k_fin2<<<1, 256, 0, stream>>>(stats, g2, be2, gsc, bsc, coef);
    k_final<<<2048, 256, 0, stream>>>(out, coef);
}

// Round 4
// 1266.126 us; speedup vs baseline: 2.5056x; 1.0631x over previous
//
#include <hip/hip_runtime.h>
#include <hip/hip_bf16.h>

typedef _Float16 f16;
typedef __attribute__((ext_vector_type(8))) _Float16 f16x8;
typedef __attribute__((ext_vector_type(4))) _Float16 f16x4;
typedef __attribute__((ext_vector_type(4))) float f32x4;

// ---------- small device helpers ----------
__device__ __forceinline__ float geluf(float x) {
    return 0.5f * x * (1.0f + erff(x * 0.70710678118654752440f));
}
__device__ __forceinline__ float sigmf(float x) { return 1.0f / (1.0f + __expf(-x)); }

// Sizes (fixed by the problem)
#define NB 16
#define NC 128
#define NH 128
#define NW 128
#define PLANE (NH * NW)          // 16384
#define NSTAT 262144.0f          // B*H*W per-channel BN count

// f16 weights / staged tensors in device-global memory (no workspace assumptions).
// g_Wc  : [tap(9)][chunk(4)][co(128)][ci32]
// g_Wsc : [chunk(4)][co(128)][ci32]
// g_W2  : [chunk(4)][co(128)][ci32]
// g_xmT : [b][h][chunk(4)][wslot(130)][ci32]   (slot = w+1; slots 0,129 zero)
// g_y1T : [b][h][cog(4)][w(128)][co32]          (conv1 out, f16)
// g_bbT : [b][h][chunk(4)][w(128)][ci32]        (silu(bn1(y1)), f16)
__device__ __align__(16) f16 g_Wc[9 * 4 * 128 * 32];
__device__ __align__(16) f16 g_Wsc[4 * 128 * 32];
__device__ __align__(16) f16 g_W2[4 * 128 * 32];
__device__ __align__(16) f16 g_xmT[(size_t)16 * 128 * 4 * 130 * 32];
__device__ __align__(16) f16 g_y1T[(size_t)16 * 128 * 4 * 128 * 32];
__device__ __align__(16) f16 g_bbT[(size_t)16 * 128 * 4 * 128 * 32];

// ---------- K0: convert conv1/sc/conv2 weights to f16 in MFMA-friendly layout ----------
__global__ __launch_bounds__(256) void k_wprep(const float* __restrict__ c1w,
                                               const float* __restrict__ scw,
                                               const float* __restrict__ c2w) {
    int i = blockIdx.x * 256 + threadIdx.x;
    if (i < 147456) {                       // 9*4*128*32
        int tap = i / 16384;
        int rem = i - tap * 16384;
        int chunk = rem >> 12;
        int r2 = rem & 4095;
        int co = r2 >> 5;
        int cil = r2 & 31;
        int ci = chunk * 32 + cil;
        g_Wc[i] = (f16)c1w[((size_t)co * 128 + ci) * 9 + tap];
    } else if (i < 163840) {                // + 4*128*32
        int j = i - 147456;
        int chunk = j >> 12;
        int r2 = j & 4095;
        int co = r2 >> 5;
        int cil = r2 & 31;
        g_Wsc[j] = (f16)scw[(size_t)co * 128 + chunk * 32 + cil];
    } else if (i < 180224) {                // + 4*128*32
        int j = i - 163840;
        int chunk = j >> 12;
        int r2 = j & 4095;
        int co = r2 >> 5;
        int cil = j & 31;
        g_W2[j] = (f16)c2w[(size_t)co * 128 + chunk * 32 + cil];
    }
}

// ---------- K1: partial dce @ W1, K-split over 128 blocks, atomicAdd into dh ----------
__global__ __launch_bounds__(256) void k_dce1(const float* __restrict__ dce,
                                              const float* __restrict__ W1,
                                              float* __restrict__ dh) {
    int ks = blockIdx.x;          // 128 slices of 100 k
    int kbase = ks * 100;
    int t = threadIdx.x;
    __shared__ float sdce[16][100];
    for (int e = t; e < 1600; e += 256) {
        int bb = e / 100, k = e - bb * 100;
        sdce[bb][k] = dce[(size_t)bb * 12800 + kbase + k];
    }
    __syncthreads();
    int j = t & 127;
    int bg = t >> 7;              // 0/1 -> b 0..7 / 8..15
    float accs[8];
#pragma unroll
    for (int i = 0; i < 8; ++i) accs[i] = 0.0f;
    for (int k = 0; k < 100; ++k) {
        float wv = W1[((size_t)(kbase + k)) * 128 + j];
#pragma unroll
        for (int bb = 0; bb < 8; ++bb) accs[bb] += sdce[bg * 8 + bb][k] * wv;
    }
#pragma unroll
    for (int bb = 0; bb < 8; ++bb)
        atomicAdd(&dh[(bg * 8 + bb) * 128 + j], accs[bb]);
}

// ---------- K2: dce_feat = gelu(dh + b1) @ W2 + b2, [16,128] ----------
__global__ __launch_bounds__(128) void k_dce2(const float* __restrict__ dh,
                                              const float* __restrict__ b1,
                                              const float* __restrict__ W2,
                                              const float* __restrict__ b2,
                                              float* __restrict__ feat) {
    int b = blockIdx.x, j = threadIdx.x;
    __shared__ float sh[128];
    sh[j] = geluf(dh[b * 128 + j] + b1[j]);
    __syncthreads();
    float acc = b2[j];
    for (int k = 0; k < 128; ++k) acc += sh[k] * W2[k * 128 + j];
    feat[b * 128 + j] = acc;
}

// ---------- K3: spatial features via border-corrected sums (shuffle reduce) ----------
__global__ __launch_bounds__(256) void k_spatial(const float* __restrict__ x,
                                                 const float* __restrict__ dw,
                                                 float* __restrict__ spat) {
    int bc = blockIdx.x;  // b*128+c
    int t = threadIdx.x;
    const float* p = x + (size_t)bc * PLANE;
    float f = 0, r0 = 0, r1 = 0, c0 = 0, c1 = 0;
    for (int i = t; i < PLANE; i += 256) {
        float v = p[i];
        int row = i >> 7, col = i & 127;
        f += v;
        if (row == 0) r0 += v;
        if (row == 127) r1 += v;
        if (col == 0) c0 += v;
        if (col == 127) c1 += v;
    }
#pragma unroll
    for (int o = 1; o < 64; o <<= 1) {
        f  += __shfl_xor(f, o);
        r0 += __shfl_xor(r0, o);
        r1 += __shfl_xor(r1, o);
        c0 += __shfl_xor(c0, o);
        c1 += __shfl_xor(c1, o);
    }
    __shared__ float wr[4][5];
    int wid = t >> 6;
    if ((t & 63) == 0) {
        wr[wid][0] = f; wr[wid][1] = r0; wr[wid][2] = r1; wr[wid][3] = c0; wr[wid][4] = c1;
    }
    __syncthreads();
    if (t == 0) {
        float full = 0, row0 = 0, row127 = 0, col0 = 0, col127 = 0;
#pragma unroll
        for (int w = 0; w < 4; ++w) {
            full += wr[w][0]; row0 += wr[w][1]; row127 += wr[w][2];
            col0 += wr[w][3]; col127 += wr[w][4];
        }
        int c = bc & 127;
        float x00 = p[0];
        float x0e = p[127];
        float xe0 = p[127 * 128];
        float xee = p[127 * 128 + 127];
        float acc = 0.0f;
        for (int kh = 0; kh < 3; ++kh)
            for (int kw = 0; kw < 3; ++kw) {
                int dh_ = kh - 1, dwv = kw - 1;
                float T = full;
                if (dh_ == -1) T -= row127;
                else if (dh_ == 1) T -= row0;
                if (dwv == -1) T -= col127;
                else if (dwv == 1) T -= col0;
                if (dh_ == -1 && dwv == -1) T += xee;
                if (dh_ == -1 && dwv == 1) T += xe0;
                if (dh_ == 1 && dwv == -1) T += x0e;
                if (dh_ == 1 && dwv == 1) T += x00;
                acc += dw[c * 9 + kh * 3 + kw] * T;
            }
        spat[bc] = acc * (1.0f / 16384.0f);
    }
}

// ---------- K4: SE modulation -> mod_w [16,128] ----------
__global__ __launch_bounds__(128) void k_mod(const float* __restrict__ feat,
                                             const float* __restrict__ spat,
                                             const float* __restrict__ Wsh,
                                             const float* __restrict__ bsh,
                                             const float* __restrict__ Wex,
                                             const float* __restrict__ bex,
                                             float* __restrict__ mod) {
    int b = blockIdx.x, t = threadIdx.x;
    __shared__ float sm[128], ssh[64];
    sm[t] = feat[b * 128 + t] * spat[b * 128 + t];
    __syncthreads();
    if (t < 64) {
        float acc = bsh[t];
        for (int c = 0; c < 128; ++c) acc += sm[c] * Wsh[c * 64 + t];
        ssh[t] = geluf(acc);
    }
    __syncthreads();
    float acc = bex[t];
    for (int k = 0; k < 64; ++k) acc += ssh[k] * Wex[k * 128 + t];
    mod[b * 128 + t] = sigmf(acc);
}

// ---------- K4b: xprep — xmT = f16(x * mod), transposed [w][ci] with halo slots ----------
__global__ __launch_bounds__(256) void k_xprep(const float* __restrict__ x,
                                               const float* __restrict__ mod) {
    int bid = blockIdx.x;  // b*128 + h
    int h = bid & 127;
    int b = bid >> 7;
    int t = threadIdx.x;
    __shared__ float sx[32][133];

    for (int chunk = 0; chunk < 4; ++chunk) {
        __syncthreads();
#pragma unroll
        for (int it = 0; it < 4; ++it) {
            int ci = it * 8 + (t >> 5);
            int w4 = t & 31;
            int cig = chunk * 32 + ci;
            float4 v = *(const float4*)&x[(((size_t)b * 128 + cig) * 128 + h) * 128 + w4 * 4];
            float m = mod[b * 128 + cig];
            sx[ci][w4 * 4 + 0] = v.x * m;
            sx[ci][w4 * 4 + 1] = v.y * m;
            sx[ci][w4 * 4 + 2] = v.z * m;
            sx[ci][w4 * 4 + 3] = v.w * m;
        }
        __syncthreads();
        f16* dstc = g_xmT + (((size_t)(b * 128 + h)) * 4 + chunk) * 4160;
        for (int g = t; g < 520; g += 256) {
            int s = g >> 2, c8 = g & 3;
            f16x8 o;
            if (s == 0 || s == 129) {
#pragma unroll
                for (int j = 0; j < 8; ++j) o[j] = (f16)0.f;
            } else {
#pragma unroll
                for (int j = 0; j < 8; ++j) o[j] = (f16)sx[c8 * 8 + j][s - 1];
            }
            *(f16x8*)(dstc + s * 32 + c8 * 8) = o;
        }
    }
}

// ---------- K5 (MFMA): conv1 3x3 -> y1T f16 + bn1 stats ----------
// Zero-LDS, zero-barrier: B fragments load directly from g_xmT (coalesced 1KB/wave),
// A fragments from L2-hot g_Wc. Fully unrolled 36-tap dataflow stream; XCD swizzle.
__global__ __launch_bounds__(256, 3) void k_conv1m(float* __restrict__ stats) {
    int orig = blockIdx.x;
    int sw = (orig & 7) * 256 + (orig >> 3);   // bijective: 2048 % 8 == 0
    int h = sw & 127;
    int b = sw >> 7;
    int t = threadIdx.x;
    int lane = t & 63;
    int wv = t >> 6;
    int l15 = lane & 15, lg = lane >> 4;
    int co_half = (wv >> 1) * 64;
    int w_half = (wv & 1) * 64;

    f32x4 acc[4][4];
#pragma unroll
    for (int ct = 0; ct < 4; ++ct)
#pragma unroll
        for (int wt = 0; wt < 4; ++wt) acc[ct][wt] = (f32x4){0.f, 0.f, 0.f, 0.f};

    f16x8 z8;
#pragma unroll
    for (int j = 0; j < 8; ++j) z8[j] = (f16)0.f;

    const f16* xrow[3];
    bool rok[3];
#pragma unroll
    for (int r = 0; r < 3; ++r) {
        int hr = h + r - 1;
        rok[r] = ((unsigned)hr < 128u);
        xrow[r] = g_xmT + ((size_t)(b * 128 + (rok[r] ? hr : 0))) * 4 * 4160;
    }

#pragma unroll
    for (int chunk = 0; chunk < 4; ++chunk) {
#pragma unroll
        for (int tap = 0; tap < 9; ++tap) {
            const int kh = tap / 3, kw = tap - kh * 3;
            f16x8 af[4], bf[4];
#pragma unroll
            for (int ct = 0; ct < 4; ++ct)
                af[ct] = *(const f16x8*)(g_Wc + ((size_t)(tap * 4 + chunk) * 128 + co_half + ct * 16 + l15) * 32 + lg * 8);
            if (rok[kh]) {
#pragma unroll
                for (int wt = 0; wt < 4; ++wt)
                    bf[wt] = *(const f16x8*)(xrow[kh] + (size_t)chunk * 4160
                                             + (w_half + wt * 16 + l15 + kw) * 32 + lg * 8);
            } else {
#pragma unroll
                for (int wt = 0; wt < 4; ++wt) bf[wt] = z8;
            }
#pragma unroll
            for (int ct = 0; ct < 4; ++ct)
#pragma unroll
                for (int wt = 0; wt < 4; ++wt)
                    acc[ct][wt] = __builtin_amdgcn_mfma_f32_16x16x32_f16(
                        af[ct], bf[wt], acc[ct][wt], 0, 0, 0);
        }
    }

    // ---- epilogue: write y1T (f16) + bn1 stats ----
#pragma unroll
    for (int ct = 0; ct < 4; ++ct) {
        int cog = (wv >> 1) * 2 + (ct >> 1);
        int col = (ct & 1) * 16 + lg * 4;
#pragma unroll
        for (int wt = 0; wt < 4; ++wt) {
            int w = w_half + wt * 16 + l15;
            f16x4 pk;
            pk[0] = (f16)acc[ct][wt][0];
            pk[1] = (f16)acc[ct][wt][1];
            pk[2] = (f16)acc[ct][wt][2];
            pk[3] = (f16)acc[ct][wt][3];
            *(f16x4*)(g_y1T + ((((size_t)(b * 128 + h)) * 4 + cog) * 128 + w) * 32 + col) = pk;
        }
#pragma unroll
        for (int r = 0; r < 4; ++r) {
            int co = co_half + ct * 16 + lg * 4 + r;
            float s = 0, q = 0;
#pragma unroll
            for (int wt = 0; wt < 4; ++wt) {
                float v = acc[ct][wt][r];
                s += v; q += v * v;
            }
#pragma unroll
            for (int o = 1; o < 16; o <<= 1) {
                s += __shfl_xor(s, o);
                q += __shfl_xor(q, o);
            }
            if (l15 == 0) {
                atomicAdd(&stats[co], s);
                atomicAdd(&stats[128 + co], q);
            }
        }
    }
}

// ---------- K6: finalize bn1 -> affine coefs ----------
__global__ __launch_bounds__(128) void k_fin1(const float* __restrict__ stats,
                                              const float* __restrict__ g1, const float* __restrict__ be1,
                                              float* __restrict__ coef) {
    int t = threadIdx.x;
    const float inv = 1.0f / NSTAT;
    float m = stats[t] * inv;
    float v = stats[128 + t] * inv - m * m;
    float a = g1[t] * rsqrtf(v + 1e-5f);
    coef[t] = a;
    coef[128 + t] = be1[t] - m * a;
}

// ---------- K7 (MFMA): conv2 (1x1) bn2-stats + sc (1x1) stats; writes bbT ----------
// Zero LDS, zero barriers: fragments straight from g_y1T/g_xmT/weights.
__global__ __launch_bounds__(256, 2) void k_conv2m(const float* __restrict__ coef,
                                                   float* __restrict__ stats) {
    int orig = blockIdx.x;
    int sw = (orig & 7) * 256 + (orig >> 3);
    int h = sw & 127;
    int b = sw >> 7;
    int t = threadIdx.x;
    int lane = t & 63;
    int wv = t >> 6;
    int l15 = lane & 15, lg = lane >> 4;
    int co_half = (wv >> 1) * 64;
    int w_half = (wv & 1) * 64;

    f32x4 acc[4][4], asc[4][4];
#pragma unroll
    for (int ct = 0; ct < 4; ++ct)
#pragma unroll
        for (int wt = 0; wt < 4; ++wt) {
            acc[ct][wt] = (f32x4){0.f, 0.f, 0.f, 0.f};
            asc[ct][wt] = (f32x4){0.f, 0.f, 0.f, 0.f};
        }

    for (int chunk = 0; chunk < 4; ++chunk) {
        float ca[8], cc[8];
#pragma unroll
        for (int j = 0; j < 8; ++j) {
            int ci = chunk * 32 + lg * 8 + j;
            ca[j] = coef[ci];
            cc[j] = coef[128 + ci];
        }
        f16x8 bfr[4], bx[4];
#pragma unroll
        for (int wt = 0; wt < 4; ++wt) {
            int w = w_half + wt * 16 + l15;
            f16x8 raw = *(const f16x8*)(g_y1T + ((((size_t)(b * 128 + h)) * 4 + chunk) * 128 + w) * 32 + lg * 8);
#pragma unroll
            for (int j = 0; j < 8; ++j) {
                float v = ca[j] * (float)raw[j] + cc[j];
                bfr[wt][j] = (f16)(v * sigmf(v));
            }
            bx[wt] = *(const f16x8*)(g_xmT + (((size_t)(b * 128 + h)) * 4 + chunk) * 4160 + (w + 1) * 32 + lg * 8);
        }
        if (wv < 2) {   // each w written once
#pragma unroll
            for (int wt = 0; wt < 4; ++wt) {
                int w = w_half + wt * 16 + l15;
                *(f16x8*)(g_bbT + ((((size_t)(b * 128 + h)) * 4 + chunk) * 128 + w) * 32 + lg * 8) = bfr[wt];
            }
        }
        f16x8 af[4], sf[4];
#pragma unroll
        for (int ct = 0; ct < 4; ++ct) {
            af[ct] = *(const f16x8*)(g_W2 + ((size_t)chunk * 128 + co_half + ct * 16 + l15) * 32 + lg * 8);
            sf[ct] = *(const f16x8*)(g_Wsc + ((size_t)chunk * 128 + co_half + ct * 16 + l15) * 32 + lg * 8);
        }
#pragma unroll
        for (int ct = 0; ct < 4; ++ct)
#pragma unroll
            for (int wt = 0; wt < 4; ++wt) {
                acc[ct][wt] = __builtin_amdgcn_mfma_f32_16x16x32_f16(
                    af[ct], bfr[wt], acc[ct][wt], 0, 0, 0);
                asc[ct][wt] = __builtin_amdgcn_mfma_f32_16x16x32_f16(
                    sf[ct], bx[wt], asc[ct][wt], 0, 0, 0);
            }
    }

    // stats: conv2 -> [512],[640]; sc -> [256],[384]
#pragma unroll
    for (int ct = 0; ct < 4; ++ct) {
#pragma unroll
        for (int r = 0; r < 4; ++r) {
            int co = co_half + ct * 16 + lg * 4 + r;
            float s = 0, q = 0, ss = 0, qq = 0;
#pragma unroll
            for (int wt = 0; wt < 4; ++wt) {
                float v = acc[ct][wt][r];
                s += v; q += v * v;
                float u = asc[ct][wt][r];
                ss += u; qq += u * u;
            }
#pragma unroll
            for (int o = 1; o < 16; o <<= 1) {
                s += __shfl_xor(s, o);
                q += __shfl_xor(q, o);
                ss += __shfl_xor(ss, o);
                qq += __shfl_xor(qq, o);
            }
            if (l15 == 0) {
                atomicAdd(&stats[512 + co], s);
                atomicAdd(&stats[640 + co], q);
                atomicAdd(&stats[256 + co], ss);
                atomicAdd(&stats[384 + co], qq);
            }
        }
    }
}

// ---------- K8: finalize bn2 + bnsc ----------
__global__ __launch_bounds__(256) void k_fin2(const float* __restrict__ stats,
                                              const float* __restrict__ g2, const float* __restrict__ be2,
                                              const float* __restrict__ gsc, const float* __restrict__ bsc,
                                              float* __restrict__ coef) {
    int t = threadIdx.x;
    const float inv = 1.0f / NSTAT;
    if (t < 128) {
        float m = stats[512 + t] * inv;
        float v = stats[640 + t] * inv - m * m;
        float a = g2[t] * rsqrtf(v + 1e-5f);
        coef[512 + t] = a;
        coef[640 + t] = be2[t] - m * a;
    } else {
        int c = t - 128;
        float m = stats[256 + c] * inv;
        float v = stats[384 + c] * inv - m * m;
        float a = gsc[c] * rsqrtf(v + 1e-5f);
        coef[256 + c] = a;
        coef[384 + c] = bsc[c] - m * a;
    }
}

// ---------- K9 (MFMA): out = silu(bn2(conv2(bb)) + bnsc(sc(xm))) ----------
// Zero LDS; reads g_bbT + g_xmT fragments; writes d_out only.
__global__ __launch_bounds__(256, 2) void k_final(float* __restrict__ out,
                                                  const float* __restrict__ coef) {
    int orig = blockIdx.x;
    int sw = (orig & 7) * 256 + (orig >> 3);
    int h = sw & 127;
    int b = sw >> 7;
    int t = threadIdx.x;
    int lane = t & 63;
    int wv = t >> 6;
    int l15 = lane & 15, lg = lane >> 4;
    int co_half = (wv >> 1) * 64;
    int w_half = (wv & 1) * 64;

    f32x4 acc[4][4], asc[4][4];
#pragma unroll
    for (int ct = 0; ct < 4; ++ct)
#pragma unroll
        for (int wt = 0; wt < 4; ++wt) {
            acc[ct][wt] = (f32x4){0.f, 0.f, 0.f, 0.f};
            asc[ct][wt] = (f32x4){0.f, 0.f, 0.f, 0.f};
        }

    for (int chunk = 0; chunk < 4; ++chunk) {
        f16x8 bf[4], bx[4], af[4], sf[4];
#pragma unroll
        for (int wt = 0; wt < 4; ++wt) {
            int w = w_half + wt * 16 + l15;
            bf[wt] = *(const f16x8*)(g_bbT + ((((size_t)(b * 128 + h)) * 4 + chunk) * 128 + w) * 32 + lg * 8);
            bx[wt] = *(const f16x8*)(g_xmT + (((size_t)(b * 128 + h)) * 4 + chunk) * 4160 + (w + 1) * 32 + lg * 8);
        }
#pragma unroll
        for (int ct = 0; ct < 4; ++ct) {
            af[ct] = *(const f16x8*)(g_W2 + ((size_t)chunk * 128 + co_half + ct * 16 + l15) * 32 + lg * 8);
            sf[ct] = *(const f16x8*)(g_Wsc + ((size_t)chunk * 128 + co_half + ct * 16 + l15) * 32 + lg * 8);
        }
#pragma unroll
        for (int ct = 0; ct < 4; ++ct)
#pragma unroll
            for (int wt = 0; wt < 4; ++wt) {
                acc[ct][wt] = __builtin_amdgcn_mfma_f32_16x16x32_f16(
                    af[ct], bf[wt], acc[ct][wt], 0, 0, 0);
                asc[ct][wt] = __builtin_amdgcn_mfma_f32_16x16x32_f16(
                    sf[ct], bx[wt], asc[ct][wt], 0, 0, 0);
            }
    }

    // epilogue: combine + silu + store
#pragma unroll
    for (int ct = 0; ct < 4; ++ct) {
#pragma unroll
        for (int r = 0; r < 4; ++r) {
            int co = co_half + ct * 16 + lg * 4 + r;
            float a2 = coef[512 + co], c2 = coef[640 + co];
            float as = coef[256 + co], cs = coef[384 + co];
#pragma unroll
            for (int wt = 0; wt < 4; ++wt) {
                float v = a2 * acc[ct][wt][r] + c2 + as * asc[ct][wt][r] + cs;
                v = v * sigmf(v);
                out[(((size_t)b * 128 + co) * 128 + h) * 128 + w_half + wt * 16 + l15] = v;
            }
        }
    }
}

// ---------- launcher ----------
extern "C" void kernel_launch(void* const* d_in, const int* in_sizes, int n_in,
                              void* d_out, int out_size, void* d_ws, size_t ws_size,
                              hipStream_t stream) {
    (void)in_sizes; (void)n_in; (void)out_size; (void)ws_size;
    const float* x    = (const float*)d_in[0];
    const float* dce  = (const float*)d_in[1];
    const float* dwc  = (const float*)d_in[2];
    const float* W1   = (const float*)d_in[3];
    const float* b1   = (const float*)d_in[4];
    const float* W2d  = (const float*)d_in[5];
    const float* b2d  = (const float*)d_in[6];
    const float* Wsh  = (const float*)d_in[7];
    const float* bsh  = (const float*)d_in[8];
    const float* Wex  = (const float*)d_in[9];
    const float* bex  = (const float*)d_in[10];
    const float* c1w  = (const float*)d_in[11];
    const float* g1   = (const float*)d_in[12];
    const float* be1  = (const float*)d_in[13];
    const float* c2w  = (const float*)d_in[14];
    const float* g2   = (const float*)d_in[15];
    const float* be2  = (const float*)d_in[16];
    const float* scw  = (const float*)d_in[17];
    const float* gsc  = (const float*)d_in[18];
    const float* bsc  = (const float*)d_in[19];

    // scratch layout in d_ws (floats):
    // [0..2048) dh  [2048..2816) stats  [2816..3584) coef
    // [3584..5632) feat  [5632..7680) spat  [7680..9728) md
    float* F = (float*)d_ws;
    float* dh    = F;
    float* stats = F + 2048;
    float* coef  = F + 2816;
    float* feat  = F + 3584;
    float* spat  = F + 5632;
    float* md    = F + 7680;

    float* out = (float*)d_out;

    hipMemsetAsync(F, 0, (2048 + 768) * sizeof(float), stream);  // dh + stats

    k_wprep<<<704, 256, 0, stream>>>(c1w, scw, c2w);
    k_dce1<<<128, 256, 0, stream>>>(dce, W1, dh);
    k_dce2<<<16, 128, 0, stream>>>(dh, b1, W2d, b2d, feat);
    k_spatial<<<2048, 256, 0, stream>>>(x, dwc, spat);
    k_mod<<<16, 128, 0, stream>>>(feat, spat, Wsh, bsh, Wex, bex, md);
    k_xprep<<<2048, 256, 0, stream>>>(x, md);
    k_conv1m<<<2048, 256, 0, stream>>>(stats);
    k_fin1<<<1, 128, 0, stream>>>(stats, g1, be1, coef);
    k_conv2m<<<2048, 256, 0, stream>>>(coef, stats);
    k_fin2<<<1, 256, 0, stream>>>(stats, g2, be2, gsc, bsc, coef);
    k_final<<<2048, 256, 0, stream>>>(out, coef);
}